// Round 8
// baseline (1999.667 us; speedup 1.0000x reference)
//
#include <hip/hip_runtime.h>
#include <hip/hip_bf16.h>

#define BB 128
#define SS 1024
#define HH 128
#define G3 384
#define NT (BB * SS)   // 131072 tokens

typedef __hip_bfloat16 bf16;
typedef unsigned int uint;
typedef _Float16 f16;
typedef f16 f16x2 __attribute__((ext_vector_type(2)));

__device__ __forceinline__ float leaky(float x) { return x >= 0.f ? x : 0.01f * x; }
__device__ __forceinline__ f16x2 u2h(uint u) { return __builtin_bit_cast(f16x2, u); }
__device__ __forceinline__ uint packh2(float a, float b) {
  f16x2 h; h.x = (f16)a; h.y = (f16)b;
  return __builtin_bit_cast(uint, h);
}
__device__ __forceinline__ uint h1(float a) {
  return (uint)__builtin_bit_cast(unsigned short, (f16)a);
}
__device__ __forceinline__ float shflx(float v, int m) { return __shfl_xor(v, m, 64); }
// wave-private LDS exchange fence: LDS ops of one wave complete in order; this
// pins the compiler and drains outstanding ds ops.
#define WSYNC() asm volatile("s_waitcnt lgkmcnt(0)" ::: "memory")

// convert a global fp32 row to NP register f16x2 pairs
template <int NP>
__device__ __forceinline__ void ldrow(const float* __restrict__ p, f16x2* w) {
#pragma unroll
  for (int i = 0; i < NP; ++i) {
    f16x2 h; h.x = (f16)p[2 * i]; h.y = (f16)p[2 * i + 1];
    w[i] = h;
  }
}
// dot: NP f16-pairs from memory (LDS or global, broadcast) vs register weights
template <int NP>
__device__ __forceinline__ float dot2l(const uint* __restrict__ x,
                                       const f16x2* __restrict__ w, float acc) {
#pragma unroll
  for (int i = 0; i < NP / 4; ++i) {
    uint4 uu = ((const uint4*)x)[i];
    acc = __builtin_amdgcn_fdot2(u2h(uu.x), w[4 * i + 0], acc, false);
    acc = __builtin_amdgcn_fdot2(u2h(uu.y), w[4 * i + 1], acc, false);
    acc = __builtin_amdgcn_fdot2(u2h(uu.z), w[4 * i + 2], acc, false);
    acc = __builtin_amdgcn_fdot2(u2h(uu.w), w[4 * i + 3], acc, false);
  }
  return acc;
}
// dot with pre-loaded uint4 activations
template <int NP>
__device__ __forceinline__ float dotreg(const uint4* __restrict__ xv,
                                        const f16x2* __restrict__ w, float acc) {
#pragma unroll
  for (int i = 0; i < NP / 4; ++i) {
    uint4 uu = xv[i];
    acc = __builtin_amdgcn_fdot2(u2h(uu.x), w[4 * i + 0], acc, false);
    acc = __builtin_amdgcn_fdot2(u2h(uu.y), w[4 * i + 1], acc, false);
    acc = __builtin_amdgcn_fdot2(u2h(uu.z), w[4 * i + 2], acc, false);
    acc = __builtin_amdgcn_fdot2(u2h(uu.w), w[4 * i + 3], acc, false);
  }
  return acc;
}

// ---------------- pre_a: encoders + attention + LN -> xnh (f16 pairs) -------
// Register weights, wave-private LDS exchange, no barriers in the loop.
__global__ __launch_bounds__(256) void pre_a(
    const float* __restrict__ obs, const float* __restrict__ me_w1,
    const float* __restrict__ me_b1, const float* __restrict__ me_w2,
    const float* __restrict__ me_b2, const float* __restrict__ ae_w1,
    const float* __restrict__ ae_b1, const float* __restrict__ ae_w2,
    const float* __restrict__ ae_b2, const float* __restrict__ ipw,
    const float* __restrict__ ipb, const float* __restrict__ opw,
    const float* __restrict__ opb, const float* __restrict__ lng,
    const float* __restrict__ lnb, uint* __restrict__ xnh) {
  __shared__ float ss[352];                 // me_w1 | me_b1 | ae_w1 | ae_b1
  __shared__ __align__(16) uint ex[4][176]; // per-wave: um32 ua16 e1 e2 ea ec (32 each)

  const int tid = threadIdx.x;
  const int wid = tid >> 6, l = tid & 63;
  if (tid < 96) ss[tid] = me_w1[tid];
  if (tid < 32) ss[96 + tid] = me_b1[tid];
  if (tid < 192) ss[128 + tid] = ae_w1[tid];
  if (tid < 32) ss[320 + tid] = ae_b1[tid];

  f16x2 wme2[16], wae2[16], wq[32], wk[32], wv[32], wop[32];
  ldrow<16>(me_w2 + l * 32, wme2);
  ldrow<16>(ae_w2 + l * 32, wae2);
  ldrow<32>(ipw + (size_t)l * 64, wq);
  ldrow<32>(ipw + (size_t)(64 + l) * 64, wk);
  ldrow<32>(ipw + (size_t)(128 + l) * 64, wv);
  ldrow<32>(opw + (size_t)l * 64, wop);
  const float bme2 = me_b2[l], bae2 = ae_b2[l];
  const float bq = ipb[l], bk = ipb[64 + l], bv = ipb[128 + l], bop = opb[l];
  const float gl = lng[l], bl = lnb[l];
  __syncthreads();  // ss ready (once, outside the loop)

  uint* um = ex[wid];       // 32: m1 pairs [0..15], m2 pairs [16..31]
  uint* ua = um + 32;       // 16
  uint* e1 = um + 48;       // 32 (M1E pairs)
  uint* e2 = um + 80;       // 32
  uint* ea = um + 112;      // 32
  uint* ec = um + 144;      // 32 (CTX pairs)

  for (int base = blockIdx.x * 4; base < NT; base += 4096) {
    const size_t token = base + wid;
    const float4* ob4 = (const float4*)(obs + token * 12);
    float4 o0 = ob4[0], o1 = ob4[1], o2 = ob4[2];

    // stage 1: encoder hidden layers (fp32, broadcast smalls)
    const int row = l & 31;
    const bool m2h = l >= 32;
    float i0 = m2h ? o0.w : o0.x, i1 = m2h ? o1.x : o0.y, i2 = m2h ? o1.y : o0.z;
    float t1 = ss[96 + row] + i0 * ss[row * 3] + i1 * ss[row * 3 + 1] + i2 * ss[row * 3 + 2];
    t1 = leaky(t1);
    float oa0 = o1.z, oa1 = o1.w, oa2 = o2.x, oa3 = o2.y, oa4 = o2.z, oa5 = o2.w;
    float ta = ss[320 + row] + oa0 * ss[128 + row * 6] + oa1 * ss[128 + row * 6 + 1] +
               oa2 * ss[128 + row * 6 + 2] + oa3 * ss[128 + row * 6 + 3] +
               oa4 * ss[128 + row * 6 + 4] + oa5 * ss[128 + row * 6 + 5];
    ta = leaky(ta);
    float t1p = shflx(t1, 1), tap = shflx(ta, 1);
    if (!(l & 1)) {
      um[l >> 1] = packh2(t1, t1p);
      if (l < 32) ua[l >> 1] = packh2(ta, tap);
    }
    WSYNC();

    // stage 2: encoder output layers
    float m1e = dot2l<16>(um, wme2, bme2);
    float m2e = dot2l<16>(um + 16, wme2, bme2);
    float ace = dot2l<16>(ua, wae2, bae2);
    float m1p = shflx(m1e, 1), m2p = shflx(m2e, 1), acp = shflx(ace, 1);
    if (!(l & 1)) {
      e1[l >> 1] = packh2(m1e, m1p);
      e2[l >> 1] = packh2(m2e, m2p);
      ea[l >> 1] = packh2(ace, acp);
    }
    WSYNC();

    // stage 3: q, k1, k2, v1, v2 (register weights)
    float q = dot2l<32>(ea, wq, bq);
    float k1 = dot2l<32>(e1, wk, bk);
    float k2 = dot2l<32>(e2, wk, bk);
    float v1 = dot2l<32>(e1, wv, bv);
    float v2 = dot2l<32>(e2, wv, bv);

    // stage 4: attention via shfl-reduce within 16-lane heads
    float p1 = q * k1, p2 = q * k2;
    p1 += shflx(p1, 1); p2 += shflx(p2, 1);
    p1 += shflx(p1, 2); p2 += shflx(p2, 2);
    p1 += shflx(p1, 4); p2 += shflx(p2, 4);
    p1 += shflx(p1, 8); p2 += shflx(p2, 8);
    float s1 = p1 * 0.25f, s2 = p2 * 0.25f;
    float mx = fmaxf(s1, s2);
    float ev1 = __expf(s1 - mx), ev2 = __expf(s2 - mx);
    float a1 = ev1 / (ev1 + ev2);
    float ctx = a1 * v1 + (1.f - a1) * v2;
    float cxp = shflx(ctx, 1);
    if (!(l & 1)) ec[l >> 1] = packh2(ctx, cxp);
    WSYNC();

    // out_proj + residual + LayerNorm -> packed f16 xn
    float ao = dot2l<32>(ec, wop, bop);
    float x = ao + ace;
    float s = x, s2s = x * x;
#pragma unroll
    for (int off = 32; off; off >>= 1) {
      s += shflx(s, off);
      s2s += shflx(s2s, off);
    }
    float mu = s * (1.f / 64.f);
    float var = s2s * (1.f / 64.f) - mu * mu;
    float rs = rsqrtf(var + 1e-5f);
    float xn = (x - mu) * rs * gl + bl;
    float xnp = shflx(xn, 1);
    if (!(l & 1)) xnh[token * 32 + (l >> 1)] = packh2(xn, xnp);
  }
}

// ---------------- pre_b: xp = xn @ W_ih.T + b_ih  (bf16 out) ----------------
__global__ __launch_bounds__(256) void pre_b(const uint* __restrict__ xnh,
                                             const float* __restrict__ wih,
                                             const float* __restrict__ bih,
                                             bf16* __restrict__ xp) {
  const int tid = threadIdx.x, wid = tid >> 6, l = tid & 63;
  f16x2 w[192];
  float bb[6];
#pragma unroll
  for (int r = 0; r < 6; ++r) {
    ldrow<32>(wih + (size_t)(r * 64 + l) * 64, w + r * 32);
    bb[r] = bih[r * 64 + l];
  }
  for (int base = blockIdx.x * 4; base < NT; base += 4096) {
    const size_t token = base + wid;
    uint4 xv[8];
    const uint4* xq = (const uint4*)(xnh + token * 32);
#pragma unroll
    for (int i = 0; i < 8; ++i) xv[i] = xq[i];  // broadcast global loads
    const size_t outb = token * G3;
#pragma unroll
    for (int r = 0; r < 6; ++r) {
      float a = dotreg<32>(xv, w + r * 32, bb[r]);
      xp[outb + r * 64 + l] = __float2bfloat16(a);
    }
  }
}

// ---------------- gru: register gates, depth-4 x prefetch, 1 raw barrier ----
__global__ __launch_bounds__(128, 1) void gru_kernel(
    const bf16* __restrict__ xp, const float* __restrict__ hs,
    const float* __restrict__ whh, const float* __restrict__ bhh,
    uint* __restrict__ gouth, float* __restrict__ hlast) {
  __shared__ __align__(16) uint hbuf[2][64];
  const int j = threadIdx.x;
  const int b = blockIdx.x;

  f16x2 wr[64], wz[64], wg[64];
  ldrow<64>(whh + (size_t)j * HH, wr);
  ldrow<64>(whh + (size_t)(HH + j) * HH, wz);
  ldrow<64>(whh + (size_t)(2 * HH + j) * HH, wg);
  const float br = bhh[j], bz = bhh[HH + j], bg = bhh[2 * HH + j];
  float hprev = hs[b * HH + j];
  if (j < 64) hbuf[0][j] = packh2(hs[b * HH + 2 * j], hs[b * HH + 2 * j + 1]);
  __syncthreads();

  const bf16* xrow = xp + (size_t)b * SS * G3 + j;
  uint* grow = gouth + (size_t)b * SS * 64;

  float pf[4][3];
#pragma unroll
  for (int s = 0; s < 4; ++s) {
    const bf16* p = xrow + (size_t)s * G3;
    pf[s][0] = __bfloat162float(p[0]);
    pf[s][1] = __bfloat162float(p[HH]);
    pf[s][2] = __bfloat162float(p[2 * HH]);
  }

  int cur = 0;
  for (int t = 0; t < SS; t += 4) {
#pragma unroll
    for (int k = 0; k < 4; ++k) {
      const int tt = t + k;
      const uint4* hb4 = (const uint4*)hbuf[cur];
      float ar = 0.f, az = 0.f, ag = 0.f;
#pragma unroll
      for (int i = 0; i < 16; ++i) {
        uint4 hh = hb4[i];  // broadcast read
        f16x2 h0 = u2h(hh.x), h1_ = u2h(hh.y), h2 = u2h(hh.z), h3 = u2h(hh.w);
        ar = __builtin_amdgcn_fdot2(h0, wr[4 * i + 0], ar, false);
        az = __builtin_amdgcn_fdot2(h0, wz[4 * i + 0], az, false);
        ag = __builtin_amdgcn_fdot2(h0, wg[4 * i + 0], ag, false);
        ar = __builtin_amdgcn_fdot2(h1_, wr[4 * i + 1], ar, false);
        az = __builtin_amdgcn_fdot2(h1_, wz[4 * i + 1], az, false);
        ag = __builtin_amdgcn_fdot2(h1_, wg[4 * i + 1], ag, false);
        ar = __builtin_amdgcn_fdot2(h2, wr[4 * i + 2], ar, false);
        az = __builtin_amdgcn_fdot2(h2, wz[4 * i + 2], az, false);
        ag = __builtin_amdgcn_fdot2(h2, wg[4 * i + 2], ag, false);
        ar = __builtin_amdgcn_fdot2(h3, wr[4 * i + 3], ar, false);
        az = __builtin_amdgcn_fdot2(h3, wz[4 * i + 3], az, false);
        ag = __builtin_amdgcn_fdot2(h3, wg[4 * i + 3], ag, false);
      }
      float r = 1.f / (1.f + __expf(-(pf[k][0] + ar + br)));
      float z = 1.f / (1.f + __expf(-(pf[k][1] + az + bz)));
      float gp = pf[k][2] + r * (ag + bg);
      float e = __expf(-2.f * fabsf(gp));
      float th = copysignf((1.f - e) / (1.f + e), gp);
      float hn = (1.f - z) * th + z * hprev;
      hprev = hn;
      // prefetch x for step tt+4 (slack ~3 steps >> HBM latency)
      if (tt + 4 < SS) {
        const bf16* p = xrow + (size_t)(tt + 4) * G3;
        pf[k][0] = __bfloat162float(p[0]);
        pf[k][1] = __bfloat162float(p[HH]);
        pf[k][2] = __bfloat162float(p[2 * HH]);
      }
      uint hb16 = h1(hn);
      uint pb = (uint)__shfl_xor((int)hb16, 1, 64);
      if (!(j & 1)) {
        uint packed = hb16 | (pb << 16);
        hbuf[cur ^ 1][j >> 1] = packed;
        grow[(size_t)tt * 64 + (j >> 1)] = packed;
      }
      // LDS-only barrier: never drain vmcnt (keeps stores+prefetch off the path)
      asm volatile("s_waitcnt lgkmcnt(0)\n\ts_barrier" ::: "memory");
      cur ^= 1;
    }
  }
  hlast[b * HH + j] = hprev;
}

// ---------------- mlp0: f0 = leaky(g @ w0.T + b0)  (f16-pair out) -----------
__global__ __launch_bounds__(256) void mlp0(const uint* __restrict__ gh,
                                            const float* __restrict__ w0,
                                            const float* __restrict__ b0,
                                            uint* __restrict__ f0h) {
  const int tid = threadIdx.x, wid = tid >> 6, l = tid & 63;
  f16x2 wa[64], wb[64];
  ldrow<64>(w0 + (size_t)l * HH, wa);
  ldrow<64>(w0 + (size_t)(64 + l) * HH, wb);
  const float ba = b0[l], bbv = b0[64 + l];
  for (int base = blockIdx.x * 4; base < NT; base += 4096) {
    const size_t token = base + wid;
    uint4 xv[16];
    const uint4* xq = (const uint4*)(gh + token * 64);
#pragma unroll
    for (int i = 0; i < 16; ++i) xv[i] = xq[i];
    float A = leaky(dotreg<64>(xv, wa, ba));
    float B = leaky(dotreg<64>(xv, wb, bbv));
    uint ha = h1(A), hb = h1(B);
    int src = (2 * l) & 63;
    uint a0 = (uint)__shfl((int)ha, src, 64), b0s = (uint)__shfl((int)hb, src, 64);
    uint a1 = (uint)__shfl((int)ha, src + 1, 64), b1s = (uint)__shfl((int)hb, src + 1, 64);
    uint lo = (l < 32) ? a0 : b0s;
    uint hi = (l < 32) ? a1 : b1s;
    f0h[token * 64 + l] = lo | (hi << 16);
  }
}

// ---------------- mlp1: value = leaky(f0@w1.T+b1) @ ow.T + ob ---------------
__global__ __launch_bounds__(256) void mlp1(const uint* __restrict__ f0h,
                                            const float* __restrict__ w1,
                                            const float* __restrict__ b1,
                                            const float* __restrict__ ow,
                                            const float* __restrict__ obp,
                                            float* __restrict__ value) {
  const int tid = threadIdx.x, wid = tid >> 6, l = tid & 63;
  f16x2 wa[64], wb[64];
  ldrow<64>(w1 + (size_t)l * HH, wa);
  ldrow<64>(w1 + (size_t)(64 + l) * HH, wb);
  const float ba = b1[l], bbv = b1[64 + l];
  const float owl = ow[l], owh = ow[64 + l];
  const float obias = obp[0];
  for (int base = blockIdx.x * 4; base < NT; base += 4096) {
    const size_t token = base + wid;
    uint4 xv[16];
    const uint4* xq = (const uint4*)(f0h + token * 64);
#pragma unroll
    for (int i = 0; i < 16; ++i) xv[i] = xq[i];
    float A = dotreg<64>(xv, wa, ba);
    float B = dotreg<64>(xv, wb, bbv);
    float p = leaky(A) * owl + leaky(B) * owh;
#pragma unroll
    for (int off = 32; off; off >>= 1) p += shflx(p, off);
    if (l == 0) value[token] = p + obias;
  }
}

__global__ void fill_sentinel(float* o, int n) {
  for (int i = blockIdx.x * blockDim.x + threadIdx.x; i < n; i += gridDim.x * blockDim.x)
    o[i] = 999.0f;
}

extern "C" void kernel_launch(void* const* d_in, const int* in_sizes, int n_in,
                              void* d_out, int out_size, void* d_ws, size_t ws_size,
                              hipStream_t stream) {
  const float* obs = (const float*)d_in[0];
  const float* hs = (const float*)d_in[1];
  const float* me_w1 = (const float*)d_in[2];
  const float* me_b1 = (const float*)d_in[3];
  const float* me_w2 = (const float*)d_in[4];
  const float* me_b2 = (const float*)d_in[5];
  const float* ae_w1 = (const float*)d_in[6];
  const float* ae_b1 = (const float*)d_in[7];
  const float* ae_w2 = (const float*)d_in[8];
  const float* ae_b2 = (const float*)d_in[9];
  const float* ipw = (const float*)d_in[10];
  const float* ipb = (const float*)d_in[11];
  const float* opw = (const float*)d_in[12];
  const float* opb = (const float*)d_in[13];
  const float* lng = (const float*)d_in[14];
  const float* lnb = (const float*)d_in[15];
  const float* wih = (const float*)d_in[16];
  const float* whh = (const float*)d_in[17];
  const float* bih = (const float*)d_in[18];
  const float* bhh = (const float*)d_in[19];
  const float* w0 = (const float*)d_in[20];
  const float* b0 = (const float*)d_in[21];
  const float* w1 = (const float*)d_in[22];
  const float* b1 = (const float*)d_in[23];
  const float* ow = (const float*)d_in[24];
  const float* ob = (const float*)d_in[25];

  // workspace (128 MiB):
  //  region A [0, 100.66MB): xp bf16 [NT,384]; later f0h uint [NT,64] (33.5MB)
  //  region B [100.66MB, 134.22MB): xnh uint [NT,32] (16.8MB); later gouth uint [NT,64] (33.5MB)
  const size_t regA_bytes = (size_t)NT * G3 * sizeof(bf16);
  const size_t regB_bytes = (size_t)NT * 64 * sizeof(uint);
  const size_t need = regA_bytes + regB_bytes;  // 134,217,728
  float* out = (float*)d_out;
  if (ws_size < need) {
    fill_sentinel<<<288, 256, 0, stream>>>(out, out_size);
    return;
  }

  char* ws = (char*)d_ws;
  bf16* xp = (bf16*)ws;
  uint* f0h = (uint*)ws;
  uint* xnh = (uint*)(ws + regA_bytes);
  uint* gouth = (uint*)(ws + regA_bytes);

  pre_a<<<1024, 256, 0, stream>>>(obs, me_w1, me_b1, me_w2, me_b2, ae_w1, ae_b1,
                                  ae_w2, ae_b2, ipw, ipb, opw, opb, lng, lnb, xnh);
  pre_b<<<1024, 256, 0, stream>>>(xnh, wih, bih, xp);
  gru_kernel<<<BB, 128, 0, stream>>>(xp, hs, whh, bhh, gouth, out + NT);
  mlp0<<<1024, 256, 0, stream>>>(gouth, w0, b0, f0h);
  mlp1<<<1024, 256, 0, stream>>>(f0h, w1, b1, ow, ob, out);
}

// Round 9
// 1404.354 us; speedup vs baseline: 1.4239x; 1.4239x over previous
//
#include <hip/hip_runtime.h>
#include <hip/hip_bf16.h>

#define BB 128
#define SS 1024
#define HH 128
#define G3 384
#define NT (BB * SS)   // 131072 tokens

typedef __hip_bfloat16 bf16;
typedef unsigned int uint;
typedef unsigned short ushort;
typedef _Float16 f16;
typedef f16 f16x2 __attribute__((ext_vector_type(2)));

__device__ __forceinline__ float leaky(float x) { return x >= 0.f ? x : 0.01f * x; }
__device__ __forceinline__ f16x2 u2h(uint u) { return __builtin_bit_cast(f16x2, u); }
__device__ __forceinline__ uint packh2(float a, float b) {
  f16x2 h; h.x = (f16)a; h.y = (f16)b;
  return __builtin_bit_cast(uint, h);
}
__device__ __forceinline__ uint h1(float a) {
  return (uint)__builtin_bit_cast(ushort, (f16)a);
}
__device__ __forceinline__ float shflx(float v, int m) { return __shfl_xor(v, m, 64); }
// wave-private LDS exchange fence
#define WSYNC() asm volatile("s_waitcnt lgkmcnt(0)" ::: "memory")

// convert a global fp32 row to NP register f16x2 pairs
template <int NP>
__device__ __forceinline__ void ldrow(const float* __restrict__ p, f16x2* w) {
#pragma unroll
  for (int i = 0; i < NP; ++i) {
    f16x2 h; h.x = (f16)p[2 * i]; h.y = (f16)p[2 * i + 1];
    w[i] = h;
  }
}
// dot: NP f16-pairs from memory (LDS or global, broadcast) vs register weights
template <int NP>
__device__ __forceinline__ float dot2l(const uint* __restrict__ x,
                                       const f16x2* __restrict__ w, float acc) {
#pragma unroll
  for (int i = 0; i < NP / 4; ++i) {
    uint4 uu = ((const uint4*)x)[i];
    acc = __builtin_amdgcn_fdot2(u2h(uu.x), w[4 * i + 0], acc, false);
    acc = __builtin_amdgcn_fdot2(u2h(uu.y), w[4 * i + 1], acc, false);
    acc = __builtin_amdgcn_fdot2(u2h(uu.z), w[4 * i + 2], acc, false);
    acc = __builtin_amdgcn_fdot2(u2h(uu.w), w[4 * i + 3], acc, false);
  }
  return acc;
}
// dot with pre-loaded uint4 activations
template <int NP>
__device__ __forceinline__ float dotreg(const uint4* __restrict__ xv,
                                        const f16x2* __restrict__ w, float acc) {
#pragma unroll
  for (int i = 0; i < NP / 4; ++i) {
    uint4 uu = xv[i];
    acc = __builtin_amdgcn_fdot2(u2h(uu.x), w[4 * i + 0], acc, false);
    acc = __builtin_amdgcn_fdot2(u2h(uu.y), w[4 * i + 1], acc, false);
    acc = __builtin_amdgcn_fdot2(u2h(uu.z), w[4 * i + 2], acc, false);
    acc = __builtin_amdgcn_fdot2(u2h(uu.w), w[4 * i + 3], acc, false);
  }
  return acc;
}

// ---------------- pre_a: encoders + attention + LN -> xnh (f16 pairs) -------
__global__ __launch_bounds__(256) void pre_a(
    const float* __restrict__ obs, const float* __restrict__ me_w1,
    const float* __restrict__ me_b1, const float* __restrict__ me_w2,
    const float* __restrict__ me_b2, const float* __restrict__ ae_w1,
    const float* __restrict__ ae_b1, const float* __restrict__ ae_w2,
    const float* __restrict__ ae_b2, const float* __restrict__ ipw,
    const float* __restrict__ ipb, const float* __restrict__ opw,
    const float* __restrict__ opb, const float* __restrict__ lng,
    const float* __restrict__ lnb, uint* __restrict__ xnh) {
  __shared__ float ss[352];
  __shared__ __align__(16) uint ex[4][176];

  const int tid = threadIdx.x;
  const int wid = tid >> 6, l = tid & 63;
  if (tid < 96) ss[tid] = me_w1[tid];
  if (tid < 32) ss[96 + tid] = me_b1[tid];
  if (tid < 192) ss[128 + tid] = ae_w1[tid];
  if (tid < 32) ss[320 + tid] = ae_b1[tid];

  f16x2 wme2[16], wae2[16], wq[32], wk[32], wv[32], wop[32];
  ldrow<16>(me_w2 + l * 32, wme2);
  ldrow<16>(ae_w2 + l * 32, wae2);
  ldrow<32>(ipw + (size_t)l * 64, wq);
  ldrow<32>(ipw + (size_t)(64 + l) * 64, wk);
  ldrow<32>(ipw + (size_t)(128 + l) * 64, wv);
  ldrow<32>(opw + (size_t)l * 64, wop);
  const float bme2 = me_b2[l], bae2 = ae_b2[l];
  const float bq = ipb[l], bk = ipb[64 + l], bv = ipb[128 + l], bop = opb[l];
  const float gl = lng[l], bl = lnb[l];
  __syncthreads();

  uint* um = ex[wid];
  uint* ua = um + 32;
  uint* e1 = um + 48;
  uint* e2 = um + 80;
  uint* ea = um + 112;
  uint* ec = um + 144;

  for (int base = blockIdx.x * 4; base < NT; base += 4096) {
    const size_t token = base + wid;
    const float4* ob4 = (const float4*)(obs + token * 12);
    float4 o0 = ob4[0], o1 = ob4[1], o2 = ob4[2];

    const int row = l & 31;
    const bool m2h = l >= 32;
    float i0 = m2h ? o0.w : o0.x, i1 = m2h ? o1.x : o0.y, i2 = m2h ? o1.y : o0.z;
    float t1 = ss[96 + row] + i0 * ss[row * 3] + i1 * ss[row * 3 + 1] + i2 * ss[row * 3 + 2];
    t1 = leaky(t1);
    float ta = ss[320 + row] + o1.z * ss[128 + row * 6] + o1.w * ss[128 + row * 6 + 1] +
               o2.x * ss[128 + row * 6 + 2] + o2.y * ss[128 + row * 6 + 3] +
               o2.z * ss[128 + row * 6 + 4] + o2.w * ss[128 + row * 6 + 5];
    ta = leaky(ta);
    float t1p = shflx(t1, 1), tap = shflx(ta, 1);
    if (!(l & 1)) {
      um[l >> 1] = packh2(t1, t1p);
      if (l < 32) ua[l >> 1] = packh2(ta, tap);
    }
    WSYNC();

    float m1e = dot2l<16>(um, wme2, bme2);
    float m2e = dot2l<16>(um + 16, wme2, bme2);
    float ace = dot2l<16>(ua, wae2, bae2);
    float m1p = shflx(m1e, 1), m2p = shflx(m2e, 1), acp = shflx(ace, 1);
    if (!(l & 1)) {
      e1[l >> 1] = packh2(m1e, m1p);
      e2[l >> 1] = packh2(m2e, m2p);
      ea[l >> 1] = packh2(ace, acp);
    }
    WSYNC();

    float q = dot2l<32>(ea, wq, bq);
    float k1 = dot2l<32>(e1, wk, bk);
    float k2 = dot2l<32>(e2, wk, bk);
    float v1 = dot2l<32>(e1, wv, bv);
    float v2 = dot2l<32>(e2, wv, bv);

    float p1 = q * k1, p2 = q * k2;
    p1 += shflx(p1, 1); p2 += shflx(p2, 1);
    p1 += shflx(p1, 2); p2 += shflx(p2, 2);
    p1 += shflx(p1, 4); p2 += shflx(p2, 4);
    p1 += shflx(p1, 8); p2 += shflx(p2, 8);
    float s1 = p1 * 0.25f, s2 = p2 * 0.25f;
    float mx = fmaxf(s1, s2);
    float ev1 = __expf(s1 - mx), ev2 = __expf(s2 - mx);
    float a1 = ev1 / (ev1 + ev2);
    float ctx = a1 * v1 + (1.f - a1) * v2;
    float cxp = shflx(ctx, 1);
    if (!(l & 1)) ec[l >> 1] = packh2(ctx, cxp);
    WSYNC();

    float ao = dot2l<32>(ec, wop, bop);
    float x = ao + ace;
    float s = x, s2s = x * x;
#pragma unroll
    for (int off = 32; off; off >>= 1) {
      s += shflx(s, off);
      s2s += shflx(s2s, off);
    }
    float mu = s * (1.f / 64.f);
    float var = s2s * (1.f / 64.f) - mu * mu;
    float rs = rsqrtf(var + 1e-5f);
    float xn = (x - mu) * rs * gl + bl;
    float xnp = shflx(xn, 1);
    if (!(l & 1)) xnh[token * 32 + (l >> 1)] = packh2(xn, xnp);
  }
}

// ---------------- pre_b: xp = xn @ W_ih.T + b_ih  (bf16 out) ----------------
__global__ __launch_bounds__(256) void pre_b(const uint* __restrict__ xnh,
                                             const float* __restrict__ wih,
                                             const float* __restrict__ bih,
                                             bf16* __restrict__ xp) {
  const int tid = threadIdx.x, wid = tid >> 6, l = tid & 63;
  f16x2 w[192];
  float bb[6];
#pragma unroll
  for (int r = 0; r < 6; ++r) {
    ldrow<32>(wih + (size_t)(r * 64 + l) * 64, w + r * 32);
    bb[r] = bih[r * 64 + l];
  }
  for (int base = blockIdx.x * 4; base < NT; base += 4096) {
    const size_t token = base + wid;
    uint4 xv[8];
    const uint4* xq = (const uint4*)(xnh + token * 32);
#pragma unroll
    for (int i = 0; i < 8; ++i) xv[i] = xq[i];
    const size_t outb = token * G3;
#pragma unroll
    for (int r = 0; r < 6; ++r) {
      float a = dotreg<32>(xv, w + r * 32, bb[r]);
      xp[outb + r * 64 + l] = __float2bfloat16(a);
    }
  }
}

// ---------------- gru: producer/consumer waves, zero VM-loads in compute ----
// 192 threads: tid<128 compute (gates in registers); tid in [128,192) stream
// the x-rows into an 8-slot LDS ring, double-pipelined (2-step load->write
// slack). Compute waves' only VM ops are stores -> never vmcnt-waited; the
// in-loop barrier drains lgkm only.
__global__ __launch_bounds__(192, 1) void gru_kernel(
    const bf16* __restrict__ xp, const float* __restrict__ hs,
    const float* __restrict__ whh, const float* __restrict__ bhh,
    ushort* __restrict__ gouth, float* __restrict__ hlast) {
  __shared__ __align__(16) uint hbuf[2][64];
  __shared__ __align__(16) uint ring[8 * 192];  // 8 slots x 384 bf16 (768 B)
  const int tid = threadIdx.x;
  const int b = blockIdx.x;
  const bool comp = tid < 128;
  const int j = tid;
  const int pid = tid - 128;

  f16x2 wr[64], wz[64], wg[64];
  float br = 0.f, bz = 0.f, bg = 0.f, hprev = 0.f;
  const uint* xr32 = (const uint*)(xp + (size_t)b * SS * G3);
  uint a0 = 0, a1 = 0, a2 = 0, c0 = 0, c1 = 0, c2 = 0;
  if (comp) {
    ldrow<64>(whh + (size_t)j * HH, wr);
    ldrow<64>(whh + (size_t)(HH + j) * HH, wz);
    ldrow<64>(whh + (size_t)(2 * HH + j) * HH, wg);
    br = bhh[j]; bz = bhh[HH + j]; bg = bhh[2 * HH + j];
    hprev = hs[b * HH + j];
    if (j < 64) hbuf[0][j] = packh2(hs[b * HH + 2 * j], hs[b * HH + 2 * j + 1]);
  } else {
    for (int s = 0; s < 4; ++s) {
      const uint* p = xr32 + s * 192 + pid * 3;
      uint v0 = p[0], v1 = p[1], v2 = p[2];
      uint* q = ring + s * 192 + pid * 3;
      q[0] = v0; q[1] = v1; q[2] = v2;
    }
    const uint* pa = xr32 + 4 * 192 + pid * 3;
    a0 = pa[0]; a1 = pa[1]; a2 = pa[2];
    const uint* pb = xr32 + 5 * 192 + pid * 3;
    c0 = pb[0]; c1 = pb[1]; c2 = pb[2];
  }
  __syncthreads();

  const ushort* ring_us = (const ushort*)ring;
  ushort* grow = gouth + (size_t)b * SS * HH;

#define CSTEP(TT, RD, WRI)                                                     \
  {                                                                            \
    const int slot = (TT) & 7;                                                 \
    uint bxr = ring_us[slot * 384 + j];                                        \
    uint bxz = ring_us[slot * 384 + 128 + j];                                  \
    uint bxg = ring_us[slot * 384 + 256 + j];                                  \
    const uint4* hb4 = (const uint4*)hbuf[RD];                                 \
    float ar = 0.f, az = 0.f, ag = 0.f;                                        \
    _Pragma("unroll") for (int i = 0; i < 16; ++i) {                           \
      uint4 hh = hb4[i];                                                       \
      f16x2 h0 = u2h(hh.x), hA = u2h(hh.y), h2 = u2h(hh.z), h3 = u2h(hh.w);    \
      ar = __builtin_amdgcn_fdot2(h0, wr[4 * i + 0], ar, false);               \
      az = __builtin_amdgcn_fdot2(h0, wz[4 * i + 0], az, false);               \
      ag = __builtin_amdgcn_fdot2(h0, wg[4 * i + 0], ag, false);               \
      ar = __builtin_amdgcn_fdot2(hA, wr[4 * i + 1], ar, false);               \
      az = __builtin_amdgcn_fdot2(hA, wz[4 * i + 1], az, false);               \
      ag = __builtin_amdgcn_fdot2(hA, wg[4 * i + 1], ag, false);               \
      ar = __builtin_amdgcn_fdot2(h2, wr[4 * i + 2], ar, false);               \
      az = __builtin_amdgcn_fdot2(h2, wz[4 * i + 2], az, false);               \
      ag = __builtin_amdgcn_fdot2(h2, wg[4 * i + 2], ag, false);               \
      ar = __builtin_amdgcn_fdot2(h3, wr[4 * i + 3], ar, false);               \
      az = __builtin_amdgcn_fdot2(h3, wz[4 * i + 3], az, false);               \
      ag = __builtin_amdgcn_fdot2(h3, wg[4 * i + 3], ag, false);               \
    }                                                                          \
    float xrf = __uint_as_float(bxr << 16);                                    \
    float xzf = __uint_as_float(bxz << 16);                                    \
    float xgf = __uint_as_float(bxg << 16);                                    \
    float r = 1.f / (1.f + __expf(-(xrf + ar + br)));                          \
    float z = 1.f / (1.f + __expf(-(xzf + az + bz)));                          \
    float gp = xgf + r * (ag + bg);                                            \
    float e = __expf(-2.f * fabsf(gp));                                        \
    float th = copysignf((1.f - e) / (1.f + e), gp);                           \
    float hn = (1.f - z) * th + z * hprev;                                     \
    hprev = hn;                                                                \
    ushort hb16 = (ushort)h1(hn);                                              \
    ((ushort*)hbuf[WRI])[j] = hb16;                                            \
    grow[(size_t)(TT)*HH + j] = hb16;                                          \
  }

#define PSTEP(TT, R0, R1, R2)                                                  \
  {                                                                            \
    const int wrow = (TT) + 4;                                                 \
    if (wrow < SS) {                                                           \
      uint* q = ring + (wrow & 7) * 192 + pid * 3;                             \
      q[0] = R0; q[1] = R1; q[2] = R2;                                         \
      const int lrow = (TT) + 6;                                               \
      if (lrow < SS) {                                                         \
        const uint* p = xr32 + lrow * 192 + pid * 3;                           \
        R0 = p[0]; R1 = p[1]; R2 = p[2];                                       \
      }                                                                        \
    }                                                                          \
  }

  for (int t = 0; t < SS; t += 2) {
    if (comp) {
      CSTEP(t, 0, 1);
    } else {
      PSTEP(t, a0, a1, a2);
    }
    asm volatile("s_waitcnt lgkmcnt(0)\n\ts_barrier" ::: "memory");
    if (comp) {
      CSTEP(t + 1, 1, 0);
    } else {
      PSTEP(t + 1, c0, c1, c2);
    }
    asm volatile("s_waitcnt lgkmcnt(0)\n\ts_barrier" ::: "memory");
  }
#undef CSTEP
#undef PSTEP
  if (comp) hlast[b * HH + j] = hprev;
}

// ---------------- mlp0: f0 = leaky(g @ w0.T + b0)  (f16-pair out) -----------
__global__ __launch_bounds__(256) void mlp0(const uint* __restrict__ gh,
                                            const float* __restrict__ w0,
                                            const float* __restrict__ b0,
                                            uint* __restrict__ f0h) {
  const int tid = threadIdx.x, wid = tid >> 6, l = tid & 63;
  f16x2 wa[64], wb[64];
  ldrow<64>(w0 + (size_t)l * HH, wa);
  ldrow<64>(w0 + (size_t)(64 + l) * HH, wb);
  const float ba = b0[l], bbv = b0[64 + l];
  for (int base = blockIdx.x * 4; base < NT; base += 4096) {
    const size_t token = base + wid;
    uint4 xv[16];
    const uint4* xq = (const uint4*)(gh + token * 64);
#pragma unroll
    for (int i = 0; i < 16; ++i) xv[i] = xq[i];
    float A = leaky(dotreg<64>(xv, wa, ba));
    float B = leaky(dotreg<64>(xv, wb, bbv));
    uint ha = h1(A), hb = h1(B);
    int src = (2 * l) & 63;
    uint a0 = (uint)__shfl((int)ha, src, 64), b0s = (uint)__shfl((int)hb, src, 64);
    uint a1 = (uint)__shfl((int)ha, src + 1, 64), b1s = (uint)__shfl((int)hb, src + 1, 64);
    uint lo = (l < 32) ? a0 : b0s;
    uint hi = (l < 32) ? a1 : b1s;
    f0h[token * 64 + l] = lo | (hi << 16);
  }
}

// ---------------- mlp1: value = leaky(f0@w1.T+b1) @ ow.T + ob ---------------
__global__ __launch_bounds__(256) void mlp1(const uint* __restrict__ f0h,
                                            const float* __restrict__ w1,
                                            const float* __restrict__ b1,
                                            const float* __restrict__ ow,
                                            const float* __restrict__ obp,
                                            float* __restrict__ value) {
  const int tid = threadIdx.x, wid = tid >> 6, l = tid & 63;
  f16x2 wa[64], wb[64];
  ldrow<64>(w1 + (size_t)l * HH, wa);
  ldrow<64>(w1 + (size_t)(64 + l) * HH, wb);
  const float ba = b1[l], bbv = b1[64 + l];
  const float owl = ow[l], owh = ow[64 + l];
  const float obias = obp[0];
  for (int base = blockIdx.x * 4; base < NT; base += 4096) {
    const size_t token = base + wid;
    uint4 xv[16];
    const uint4* xq = (const uint4*)(f0h + token * 64);
#pragma unroll
    for (int i = 0; i < 16; ++i) xv[i] = xq[i];
    float A = dotreg<64>(xv, wa, ba);
    float B = dotreg<64>(xv, wb, bbv);
    float p = leaky(A) * owl + leaky(B) * owh;
#pragma unroll
    for (int off = 32; off; off >>= 1) p += shflx(p, off);
    if (l == 0) value[token] = p + obias;
  }
}

__global__ void fill_sentinel(float* o, int n) {
  for (int i = blockIdx.x * blockDim.x + threadIdx.x; i < n; i += gridDim.x * blockDim.x)
    o[i] = 999.0f;
}

extern "C" void kernel_launch(void* const* d_in, const int* in_sizes, int n_in,
                              void* d_out, int out_size, void* d_ws, size_t ws_size,
                              hipStream_t stream) {
  const float* obs = (const float*)d_in[0];
  const float* hs = (const float*)d_in[1];
  const float* me_w1 = (const float*)d_in[2];
  const float* me_b1 = (const float*)d_in[3];
  const float* me_w2 = (const float*)d_in[4];
  const float* me_b2 = (const float*)d_in[5];
  const float* ae_w1 = (const float*)d_in[6];
  const float* ae_b1 = (const float*)d_in[7];
  const float* ae_w2 = (const float*)d_in[8];
  const float* ae_b2 = (const float*)d_in[9];
  const float* ipw = (const float*)d_in[10];
  const float* ipb = (const float*)d_in[11];
  const float* opw = (const float*)d_in[12];
  const float* opb = (const float*)d_in[13];
  const float* lng = (const float*)d_in[14];
  const float* lnb = (const float*)d_in[15];
  const float* wih = (const float*)d_in[16];
  const float* whh = (const float*)d_in[17];
  const float* bih = (const float*)d_in[18];
  const float* bhh = (const float*)d_in[19];
  const float* w0 = (const float*)d_in[20];
  const float* b0 = (const float*)d_in[21];
  const float* w1 = (const float*)d_in[22];
  const float* b1 = (const float*)d_in[23];
  const float* ow = (const float*)d_in[24];
  const float* ob = (const float*)d_in[25];

  // workspace (128 MiB):
  //  region A [0, 100.66MB): xp bf16 [NT,384]; later f0h uint [NT,64]
  //  region B [100.66MB, 134.22MB): xnh uint [NT,32]; later gouth f16 [NT,128]
  const size_t regA_bytes = (size_t)NT * G3 * sizeof(bf16);
  const size_t regB_bytes = (size_t)NT * 64 * sizeof(uint);
  const size_t need = regA_bytes + regB_bytes;  // 134,217,728
  float* out = (float*)d_out;
  if (ws_size < need) {
    fill_sentinel<<<288, 256, 0, stream>>>(out, out_size);
    return;
  }

  char* ws = (char*)d_ws;
  bf16* xp = (bf16*)ws;
  uint* f0h = (uint*)ws;
  uint* xnh = (uint*)(ws + regA_bytes);
  ushort* gouth = (ushort*)(ws + regA_bytes);

  pre_a<<<1024, 256, 0, stream>>>(obs, me_w1, me_b1, me_w2, me_b2, ae_w1, ae_b1,
                                  ae_w2, ae_b2, ipw, ipb, opw, opb, lng, lnb, xnh);
  pre_b<<<1024, 256, 0, stream>>>(xnh, wih, bih, xp);
  gru_kernel<<<BB, 192, 0, stream>>>(xp, hs, whh, bhh, gouth, out + NT);
  mlp0<<<1024, 256, 0, stream>>>((const uint*)gouth, w0, b0, f0h);
  mlp1<<<1024, 256, 0, stream>>>(f0h, w1, b1, ow, ob, out);
}

// Round 10
// 1193.580 us; speedup vs baseline: 1.6754x; 1.1766x over previous
//
#include <hip/hip_runtime.h>
#include <hip/hip_bf16.h>

#define BB 128
#define SS 1024
#define HH 128
#define G3 384
#define NT (BB * SS)   // 131072 tokens

typedef __hip_bfloat16 bf16;
typedef unsigned int uint;
typedef unsigned short ushort;
typedef _Float16 f16;
typedef f16 f16x2 __attribute__((ext_vector_type(2)));

__device__ __forceinline__ float leaky(float x) { return x >= 0.f ? x : 0.01f * x; }
__device__ __forceinline__ f16x2 u2h(uint u) { return __builtin_bit_cast(f16x2, u); }
__device__ __forceinline__ uint packh2(float a, float b) {
  f16x2 h; h.x = (f16)a; h.y = (f16)b;
  return __builtin_bit_cast(uint, h);
}
__device__ __forceinline__ uint h1(float a) {
  return (uint)__builtin_bit_cast(ushort, (f16)a);
}
__device__ __forceinline__ float shflx(float v, int m) { return __shfl_xor(v, m, 64); }
// lane-pair exchange via quad_perm DPP [1,0,3,2] (VALU, no LDS/bpermute)
__device__ __forceinline__ float dpp_xor1(float v) {
  int i = __builtin_bit_cast(int, v);
  i = __builtin_amdgcn_update_dpp(0, i, 0xB1, 0xF, 0xF, true);
  return __builtin_bit_cast(float, i);
}
// wave-private LDS exchange fence
#define WSYNC() asm volatile("s_waitcnt lgkmcnt(0)" ::: "memory")

// convert a global fp32 row to NP register f16x2 pairs
template <int NP>
__device__ __forceinline__ void ldrow(const float* __restrict__ p, f16x2* w) {
#pragma unroll
  for (int i = 0; i < NP; ++i) {
    f16x2 h; h.x = (f16)p[2 * i]; h.y = (f16)p[2 * i + 1];
    w[i] = h;
  }
}
// dot: NP f16-pairs from memory (LDS or global, broadcast) vs register weights
template <int NP>
__device__ __forceinline__ float dot2l(const uint* __restrict__ x,
                                       const f16x2* __restrict__ w, float acc) {
#pragma unroll
  for (int i = 0; i < NP / 4; ++i) {
    uint4 uu = ((const uint4*)x)[i];
    acc = __builtin_amdgcn_fdot2(u2h(uu.x), w[4 * i + 0], acc, false);
    acc = __builtin_amdgcn_fdot2(u2h(uu.y), w[4 * i + 1], acc, false);
    acc = __builtin_amdgcn_fdot2(u2h(uu.z), w[4 * i + 2], acc, false);
    acc = __builtin_amdgcn_fdot2(u2h(uu.w), w[4 * i + 3], acc, false);
  }
  return acc;
}
// dot with pre-loaded uint4 activations
template <int NP>
__device__ __forceinline__ float dotreg(const uint4* __restrict__ xv,
                                        const f16x2* __restrict__ w, float acc) {
#pragma unroll
  for (int i = 0; i < NP / 4; ++i) {
    uint4 uu = xv[i];
    acc = __builtin_amdgcn_fdot2(u2h(uu.x), w[4 * i + 0], acc, false);
    acc = __builtin_amdgcn_fdot2(u2h(uu.y), w[4 * i + 1], acc, false);
    acc = __builtin_amdgcn_fdot2(u2h(uu.z), w[4 * i + 2], acc, false);
    acc = __builtin_amdgcn_fdot2(u2h(uu.w), w[4 * i + 3], acc, false);
  }
  return acc;
}

// ---------------- pre_a: encoders + attention + LN -> xnh (f16 pairs) -------
__global__ __launch_bounds__(256) void pre_a(
    const float* __restrict__ obs, const float* __restrict__ me_w1,
    const float* __restrict__ me_b1, const float* __restrict__ me_w2,
    const float* __restrict__ me_b2, const float* __restrict__ ae_w1,
    const float* __restrict__ ae_b1, const float* __restrict__ ae_w2,
    const float* __restrict__ ae_b2, const float* __restrict__ ipw,
    const float* __restrict__ ipb, const float* __restrict__ opw,
    const float* __restrict__ opb, const float* __restrict__ lng,
    const float* __restrict__ lnb, uint* __restrict__ xnh) {
  __shared__ float ss[352];
  __shared__ __align__(16) uint ex[4][176];

  const int tid = threadIdx.x;
  const int wid = tid >> 6, l = tid & 63;
  if (tid < 96) ss[tid] = me_w1[tid];
  if (tid < 32) ss[96 + tid] = me_b1[tid];
  if (tid < 192) ss[128 + tid] = ae_w1[tid];
  if (tid < 32) ss[320 + tid] = ae_b1[tid];

  f16x2 wme2[16], wae2[16], wq[32], wk[32], wv[32], wop[32];
  ldrow<16>(me_w2 + l * 32, wme2);
  ldrow<16>(ae_w2 + l * 32, wae2);
  ldrow<32>(ipw + (size_t)l * 64, wq);
  ldrow<32>(ipw + (size_t)(64 + l) * 64, wk);
  ldrow<32>(ipw + (size_t)(128 + l) * 64, wv);
  ldrow<32>(opw + (size_t)l * 64, wop);
  const float bme2 = me_b2[l], bae2 = ae_b2[l];
  const float bq = ipb[l], bk = ipb[64 + l], bv = ipb[128 + l], bop = opb[l];
  const float gl = lng[l], bl = lnb[l];
  __syncthreads();

  uint* um = ex[wid];
  uint* ua = um + 32;
  uint* e1 = um + 48;
  uint* e2 = um + 80;
  uint* ea = um + 112;
  uint* ec = um + 144;

  for (int base = blockIdx.x * 4; base < NT; base += 4096) {
    const size_t token = base + wid;
    const float4* ob4 = (const float4*)(obs + token * 12);
    float4 o0 = ob4[0], o1 = ob4[1], o2 = ob4[2];

    const int row = l & 31;
    const bool m2h = l >= 32;
    float i0 = m2h ? o0.w : o0.x, i1 = m2h ? o1.x : o0.y, i2 = m2h ? o1.y : o0.z;
    float t1 = ss[96 + row] + i0 * ss[row * 3] + i1 * ss[row * 3 + 1] + i2 * ss[row * 3 + 2];
    t1 = leaky(t1);
    float ta = ss[320 + row] + o1.z * ss[128 + row * 6] + o1.w * ss[128 + row * 6 + 1] +
               o2.x * ss[128 + row * 6 + 2] + o2.y * ss[128 + row * 6 + 3] +
               o2.z * ss[128 + row * 6 + 4] + o2.w * ss[128 + row * 6 + 5];
    ta = leaky(ta);
    float t1p = shflx(t1, 1), tap = shflx(ta, 1);
    if (!(l & 1)) {
      um[l >> 1] = packh2(t1, t1p);
      if (l < 32) ua[l >> 1] = packh2(ta, tap);
    }
    WSYNC();

    float m1e = dot2l<16>(um, wme2, bme2);
    float m2e = dot2l<16>(um + 16, wme2, bme2);
    float ace = dot2l<16>(ua, wae2, bae2);
    float m1p = shflx(m1e, 1), m2p = shflx(m2e, 1), acp = shflx(ace, 1);
    if (!(l & 1)) {
      e1[l >> 1] = packh2(m1e, m1p);
      e2[l >> 1] = packh2(m2e, m2p);
      ea[l >> 1] = packh2(ace, acp);
    }
    WSYNC();

    float q = dot2l<32>(ea, wq, bq);
    float k1 = dot2l<32>(e1, wk, bk);
    float k2 = dot2l<32>(e2, wk, bk);
    float v1 = dot2l<32>(e1, wv, bv);
    float v2 = dot2l<32>(e2, wv, bv);

    float p1 = q * k1, p2 = q * k2;
    p1 += shflx(p1, 1); p2 += shflx(p2, 1);
    p1 += shflx(p1, 2); p2 += shflx(p2, 2);
    p1 += shflx(p1, 4); p2 += shflx(p2, 4);
    p1 += shflx(p1, 8); p2 += shflx(p2, 8);
    float s1 = p1 * 0.25f, s2 = p2 * 0.25f;
    float mx = fmaxf(s1, s2);
    float ev1 = __expf(s1 - mx), ev2 = __expf(s2 - mx);
    float a1 = ev1 / (ev1 + ev2);
    float ctx = a1 * v1 + (1.f - a1) * v2;
    float cxp = shflx(ctx, 1);
    if (!(l & 1)) ec[l >> 1] = packh2(ctx, cxp);
    WSYNC();

    float ao = dot2l<32>(ec, wop, bop);
    float x = ao + ace;
    float s = x, s2s = x * x;
#pragma unroll
    for (int off = 32; off; off >>= 1) {
      s += shflx(s, off);
      s2s += shflx(s2s, off);
    }
    float mu = s * (1.f / 64.f);
    float var = s2s * (1.f / 64.f) - mu * mu;
    float rs = rsqrtf(var + 1e-5f);
    float xn = (x - mu) * rs * gl + bl;
    float xnp = shflx(xn, 1);
    if (!(l & 1)) xnh[token * 32 + (l >> 1)] = packh2(xn, xnp);
  }
}

// ---------------- pre_b: xp = xn @ W_ih.T + b_ih  (bf16 out) ----------------
__global__ __launch_bounds__(256) void pre_b(const uint* __restrict__ xnh,
                                             const float* __restrict__ wih,
                                             const float* __restrict__ bih,
                                             bf16* __restrict__ xp) {
  const int tid = threadIdx.x, wid = tid >> 6, l = tid & 63;
  f16x2 w[192];
  float bb[6];
#pragma unroll
  for (int r = 0; r < 6; ++r) {
    ldrow<32>(wih + (size_t)(r * 64 + l) * 64, w + r * 32);
    bb[r] = bih[r * 64 + l];
  }
  for (int base = blockIdx.x * 4; base < NT; base += 4096) {
    const size_t token = base + wid;
    uint4 xv[8];
    const uint4* xq = (const uint4*)(xnh + token * 32);
#pragma unroll
    for (int i = 0; i < 8; ++i) xv[i] = xq[i];
    const size_t outb = token * G3;
#pragma unroll
    for (int r = 0; r < 6; ++r) {
      float a = dotreg<32>(xv, w + r * 32, bb[r]);
      xp[outb + r * 64 + l] = __float2bfloat16(a);
    }
  }
}

// ---------------- gru: lane-pair split-k + DPP combine, 1 barrier/step ------
// 320 threads: waves 0-3 compute (lane pair (2m,2m+1) splits h into halves for
// output j = w*32+m; 96 fdot2/lane; DPP xor-1 combines partials; gates
// computed redundantly by both lanes; even lane publishes h + gout). Wave 4
// streams x rows into the 8-slot LDS ring (per-wave vmcnt, invisible to
// compute). One lgkm-only barrier per step; h double-buffered.
__global__ __launch_bounds__(320, 1) void gru_kernel(
    const bf16* __restrict__ xp, const float* __restrict__ hs,
    const float* __restrict__ whh, const float* __restrict__ bhh,
    ushort* __restrict__ gouth, float* __restrict__ hlast) {
  __shared__ __align__(16) uint hbuf[2][64];
  __shared__ __align__(16) uint ring[8 * 192];  // 8 slots x 384 bf16 (768 B)
  const int tid = threadIdx.x;
  const int b = blockIdx.x;
  const bool comp = tid < 256;
  const int lane = tid & 63;
  const int wv_ = tid >> 6;
  const int m = lane >> 1;
  const int par = lane & 1;            // k-half
  const int j = (wv_ << 5) + m;        // output index 0..127 (waves 0-3)
  const int pid = tid - 256;           // producer lane 0..63

  f16x2 wr[32], wz[32], wg[32];
  float br = 0.f, bz = 0.f, bg = 0.f, hprev = 0.f;
  const uint* xr32 = (const uint*)(xp + (size_t)b * SS * G3);
  uint a0 = 0, a1 = 0, a2 = 0, c0 = 0, c1 = 0, c2 = 0;
  if (comp) {
    ldrow<32>(whh + (size_t)j * HH + par * 64, wr);
    ldrow<32>(whh + (size_t)(HH + j) * HH + par * 64, wz);
    ldrow<32>(whh + (size_t)(2 * HH + j) * HH + par * 64, wg);
    br = bhh[j]; bz = bhh[HH + j]; bg = bhh[2 * HH + j];
    hprev = hs[b * HH + j];
    if (tid < 64) hbuf[0][tid] = packh2(hs[b * HH + 2 * tid], hs[b * HH + 2 * tid + 1]);
  } else {
    for (int s = 0; s < 4; ++s) {
      const uint* p = xr32 + s * 192 + pid * 3;
      uint v0 = p[0], v1 = p[1], v2 = p[2];
      uint* q = ring + s * 192 + pid * 3;
      q[0] = v0; q[1] = v1; q[2] = v2;
    }
    const uint* pa = xr32 + 4 * 192 + pid * 3;
    a0 = pa[0]; a1 = pa[1]; a2 = pa[2];
    const uint* pb = xr32 + 5 * 192 + pid * 3;
    c0 = pb[0]; c1 = pb[1]; c2 = pb[2];
  }
  __syncthreads();

  const ushort* ring_us = (const ushort*)ring;
  ushort* grow = gouth + (size_t)b * SS * HH;

#define CSTEP(TT, RD, WRI)                                                     \
  {                                                                            \
    const int slot = (TT) & 7;                                                 \
    uint bxr = ring_us[slot * 384 + j];                                        \
    uint bxz = ring_us[slot * 384 + 128 + j];                                  \
    uint bxg = ring_us[slot * 384 + 256 + j];                                  \
    const uint4* hb4 = (const uint4*)(hbuf[RD] + par * 32);                    \
    float ar = 0.f, az = 0.f, ag = 0.f;                                        \
    _Pragma("unroll") for (int i = 0; i < 8; ++i) {                            \
      uint4 hh = hb4[i];                                                       \
      f16x2 h0 = u2h(hh.x), hA = u2h(hh.y), h2 = u2h(hh.z), h3 = u2h(hh.w);    \
      ar = __builtin_amdgcn_fdot2(h0, wr[4 * i + 0], ar, false);               \
      az = __builtin_amdgcn_fdot2(h0, wz[4 * i + 0], az, false);               \
      ag = __builtin_amdgcn_fdot2(h0, wg[4 * i + 0], ag, false);               \
      ar = __builtin_amdgcn_fdot2(hA, wr[4 * i + 1], ar, false);               \
      az = __builtin_amdgcn_fdot2(hA, wz[4 * i + 1], az, false);               \
      ag = __builtin_amdgcn_fdot2(hA, wg[4 * i + 1], ag, false);               \
      ar = __builtin_amdgcn_fdot2(h2, wr[4 * i + 2], ar, false);               \
      az = __builtin_amdgcn_fdot2(h2, wz[4 * i + 2], az, false);               \
      ag = __builtin_amdgcn_fdot2(h2, wg[4 * i + 2], ag, false);               \
      ar = __builtin_amdgcn_fdot2(h3, wr[4 * i + 3], ar, false);               \
      az = __builtin_amdgcn_fdot2(h3, wz[4 * i + 3], az, false);               \
      ag = __builtin_amdgcn_fdot2(h3, wg[4 * i + 3], ag, false);               \
    }                                                                          \
    ar += dpp_xor1(ar); az += dpp_xor1(az); ag += dpp_xor1(ag);                \
    float xrf = __uint_as_float(bxr << 16);                                    \
    float xzf = __uint_as_float(bxz << 16);                                    \
    float xgf = __uint_as_float(bxg << 16);                                    \
    float r = 1.f / (1.f + __expf(-(xrf + ar + br)));                          \
    float z = 1.f / (1.f + __expf(-(xzf + az + bz)));                          \
    float gp = xgf + r * (ag + bg);                                            \
    float e = __expf(-2.f * fabsf(gp));                                        \
    float th = copysignf((1.f - e) / (1.f + e), gp);                           \
    float hn = (1.f - z) * th + z * hprev;                                     \
    hprev = hn;                                                                \
    if (!par) {                                                                \
      ushort hb16 = (ushort)h1(hn);                                            \
      ((ushort*)hbuf[WRI])[j] = hb16;                                          \
      grow[(size_t)(TT)*HH + j] = hb16;                                        \
    }                                                                          \
  }

#define PSTEP(TT, R0, R1, R2)                                                  \
  {                                                                            \
    const int wrow = (TT) + 4;                                                 \
    if (wrow < SS) {                                                           \
      uint* q = ring + (wrow & 7) * 192 + pid * 3;                             \
      q[0] = R0; q[1] = R1; q[2] = R2;                                         \
      const int lrow = (TT) + 6;                                               \
      if (lrow < SS) {                                                         \
        const uint* p = xr32 + lrow * 192 + pid * 3;                           \
        R0 = p[0]; R1 = p[1]; R2 = p[2];                                       \
      }                                                                        \
    }                                                                          \
  }

  for (int t = 0; t < SS; t += 2) {
    if (comp) {
      CSTEP(t, 0, 1);
    } else {
      PSTEP(t, a0, a1, a2);
    }
    asm volatile("s_waitcnt lgkmcnt(0)\n\ts_barrier" ::: "memory");
    if (comp) {
      CSTEP(t + 1, 1, 0);
    } else {
      PSTEP(t + 1, c0, c1, c2);
    }
    asm volatile("s_waitcnt lgkmcnt(0)\n\ts_barrier" ::: "memory");
  }
#undef CSTEP
#undef PSTEP
  if (comp && !par) hlast[b * HH + j] = hprev;
}

// ---------------- mlp0: f0 = leaky(g @ w0.T + b0)  (f16-pair out) -----------
__global__ __launch_bounds__(256) void mlp0(const uint* __restrict__ gh,
                                            const float* __restrict__ w0,
                                            const float* __restrict__ b0,
                                            uint* __restrict__ f0h) {
  const int tid = threadIdx.x, wid = tid >> 6, l = tid & 63;
  f16x2 wa[64], wb[64];
  ldrow<64>(w0 + (size_t)l * HH, wa);
  ldrow<64>(w0 + (size_t)(64 + l) * HH, wb);
  const float ba = b0[l], bbv = b0[64 + l];
  for (int base = blockIdx.x * 4; base < NT; base += 4096) {
    const size_t token = base + wid;
    uint4 xv[16];
    const uint4* xq = (const uint4*)(gh + token * 64);
#pragma unroll
    for (int i = 0; i < 16; ++i) xv[i] = xq[i];
    float A = leaky(dotreg<64>(xv, wa, ba));
    float B = leaky(dotreg<64>(xv, wb, bbv));
    uint ha = h1(A), hb = h1(B);
    int src = (2 * l) & 63;
    uint a0 = (uint)__shfl((int)ha, src, 64), b0s = (uint)__shfl((int)hb, src, 64);
    uint a1 = (uint)__shfl((int)ha, src + 1, 64), b1s = (uint)__shfl((int)hb, src + 1, 64);
    uint lo = (l < 32) ? a0 : b0s;
    uint hi = (l < 32) ? a1 : b1s;
    f0h[token * 64 + l] = lo | (hi << 16);
  }
}

// ---------------- mlp1: value = leaky(f0@w1.T+b1) @ ow.T + ob ---------------
__global__ __launch_bounds__(256) void mlp1(const uint* __restrict__ f0h,
                                            const float* __restrict__ w1,
                                            const float* __restrict__ b1,
                                            const float* __restrict__ ow,
                                            const float* __restrict__ obp,
                                            float* __restrict__ value) {
  const int tid = threadIdx.x, wid = tid >> 6, l = tid & 63;
  f16x2 wa[64], wb[64];
  ldrow<64>(w1 + (size_t)l * HH, wa);
  ldrow<64>(w1 + (size_t)(64 + l) * HH, wb);
  const float ba = b1[l], bbv = b1[64 + l];
  const float owl = ow[l], owh = ow[64 + l];
  const float obias = obp[0];
  for (int base = blockIdx.x * 4; base < NT; base += 4096) {
    const size_t token = base + wid;
    uint4 xv[16];
    const uint4* xq = (const uint4*)(f0h + token * 64);
#pragma unroll
    for (int i = 0; i < 16; ++i) xv[i] = xq[i];
    float A = dotreg<64>(xv, wa, ba);
    float B = dotreg<64>(xv, wb, bbv);
    float p = leaky(A) * owl + leaky(B) * owh;
#pragma unroll
    for (int off = 32; off; off >>= 1) p += shflx(p, off);
    if (l == 0) value[token] = p + obias;
  }
}

__global__ void fill_sentinel(float* o, int n) {
  for (int i = blockIdx.x * blockDim.x + threadIdx.x; i < n; i += gridDim.x * blockDim.x)
    o[i] = 999.0f;
}

extern "C" void kernel_launch(void* const* d_in, const int* in_sizes, int n_in,
                              void* d_out, int out_size, void* d_ws, size_t ws_size,
                              hipStream_t stream) {
  const float* obs = (const float*)d_in[0];
  const float* hs = (const float*)d_in[1];
  const float* me_w1 = (const float*)d_in[2];
  const float* me_b1 = (const float*)d_in[3];
  const float* me_w2 = (const float*)d_in[4];
  const float* me_b2 = (const float*)d_in[5];
  const float* ae_w1 = (const float*)d_in[6];
  const float* ae_b1 = (const float*)d_in[7];
  const float* ae_w2 = (const float*)d_in[8];
  const float* ae_b2 = (const float*)d_in[9];
  const float* ipw = (const float*)d_in[10];
  const float* ipb = (const float*)d_in[11];
  const float* opw = (const float*)d_in[12];
  const float* opb = (const float*)d_in[13];
  const float* lng = (const float*)d_in[14];
  const float* lnb = (const float*)d_in[15];
  const float* wih = (const float*)d_in[16];
  const float* whh = (const float*)d_in[17];
  const float* bih = (const float*)d_in[18];
  const float* bhh = (const float*)d_in[19];
  const float* w0 = (const float*)d_in[20];
  const float* b0 = (const float*)d_in[21];
  const float* w1 = (const float*)d_in[22];
  const float* b1 = (const float*)d_in[23];
  const float* ow = (const float*)d_in[24];
  const float* ob = (const float*)d_in[25];

  // workspace (128 MiB):
  //  region A [0, 100.66MB): xp bf16 [NT,384]; later f0h uint [NT,64]
  //  region B [100.66MB, 134.22MB): xnh uint [NT,32]; later gouth f16 [NT,128]
  const size_t regA_bytes = (size_t)NT * G3 * sizeof(bf16);
  const size_t regB_bytes = (size_t)NT * 64 * sizeof(uint);
  const size_t need = regA_bytes + regB_bytes;  // 134,217,728
  float* out = (float*)d_out;
  if (ws_size < need) {
    fill_sentinel<<<288, 256, 0, stream>>>(out, out_size);
    return;
  }

  char* ws = (char*)d_ws;
  bf16* xp = (bf16*)ws;
  uint* f0h = (uint*)ws;
  uint* xnh = (uint*)(ws + regA_bytes);
  ushort* gouth = (ushort*)(ws + regA_bytes);

  pre_a<<<1024, 256, 0, stream>>>(obs, me_w1, me_b1, me_w2, me_b2, ae_w1, ae_b1,
                                  ae_w2, ae_b2, ipw, ipb, opw, opb, lng, lnb, xnh);
  pre_b<<<1024, 256, 0, stream>>>(xnh, wih, bih, xp);
  gru_kernel<<<BB, 320, 0, stream>>>(xp, hs, whh, bhh, gouth, out + NT);
  mlp0<<<1024, 256, 0, stream>>>((const uint*)gouth, w0, b0, f0h);
  mlp1<<<1024, 256, 0, stream>>>(f0h, w1, b1, ow, ob, out);
}

// Round 11
// 962.619 us; speedup vs baseline: 2.0773x; 1.2399x over previous
//
#include <hip/hip_runtime.h>
#include <hip/hip_bf16.h>

#define BB 128
#define SS 1024
#define HH 128
#define G3 384
#define NT (BB * SS)   // 131072 tokens

typedef __hip_bfloat16 bf16;
typedef unsigned int uint;
typedef unsigned short ushort;
typedef _Float16 f16;
typedef f16 f16x2 __attribute__((ext_vector_type(2)));
typedef f16 f16x8 __attribute__((ext_vector_type(8)));
typedef float f32x4 __attribute__((ext_vector_type(4)));

__device__ __forceinline__ float leaky(float x) { return x >= 0.f ? x : 0.01f * x; }
__device__ __forceinline__ f16x2 u2h(uint u) { return __builtin_bit_cast(f16x2, u); }
__device__ __forceinline__ uint packh2(float a, float b) {
  f16x2 h; h.x = (f16)a; h.y = (f16)b;
  return __builtin_bit_cast(uint, h);
}
__device__ __forceinline__ uint h1(float a) {
  return (uint)__builtin_bit_cast(ushort, (f16)a);
}
__device__ __forceinline__ uint bf_rne(float f) {
  uint u = __float_as_uint(f);
  return (u + 0x7FFFu + ((u >> 16) & 1u)) >> 16;
}
__device__ __forceinline__ float shflx(float v, int m) { return __shfl_xor(v, m, 64); }
// lane-pair exchange via quad_perm DPP [1,0,3,2]
__device__ __forceinline__ float dpp_xor1(float v) {
  int i = __builtin_bit_cast(int, v);
  i = __builtin_amdgcn_update_dpp(0, i, 0xB1, 0xF, 0xF, true);
  return __builtin_bit_cast(float, i);
}
__device__ __forceinline__ uint dpp_xor1_u(uint v) {
  int i = __builtin_amdgcn_update_dpp(0, (int)v, 0xB1, 0xF, 0xF, true);
  return (uint)i;
}
#define WSYNC() asm volatile("s_waitcnt lgkmcnt(0)" ::: "memory")

// fp32 row -> register f16x2 pairs
template <int NP>
__device__ __forceinline__ void ldrow(const float* __restrict__ p, f16x2* w) {
#pragma unroll
  for (int i = 0; i < NP; ++i) {
    f16x2 h; h.x = (f16)p[2 * i]; h.y = (f16)p[2 * i + 1];
    w[i] = h;
  }
}
// 8 contiguous fp32 -> one f16x8 MFMA fragment chunk
__device__ __forceinline__ f16x8 ldw8(const float* __restrict__ p) {
  f16x8 v;
#pragma unroll
  for (int j = 0; j < 8; ++j) v[j] = (f16)p[j];
  return v;
}
template <int NP>
__device__ __forceinline__ float dot2l(const uint* __restrict__ x,
                                       const f16x2* __restrict__ w, float acc) {
#pragma unroll
  for (int i = 0; i < NP / 4; ++i) {
    uint4 uu = ((const uint4*)x)[i];
    acc = __builtin_amdgcn_fdot2(u2h(uu.x), w[4 * i + 0], acc, false);
    acc = __builtin_amdgcn_fdot2(u2h(uu.y), w[4 * i + 1], acc, false);
    acc = __builtin_amdgcn_fdot2(u2h(uu.z), w[4 * i + 2], acc, false);
    acc = __builtin_amdgcn_fdot2(u2h(uu.w), w[4 * i + 3], acc, false);
  }
  return acc;
}

// ---------------- pre_a: encoders + attention + LN -> xnh (f16 pairs) -------
__global__ __launch_bounds__(256) void pre_a(
    const float* __restrict__ obs, const float* __restrict__ me_w1,
    const float* __restrict__ me_b1, const float* __restrict__ me_w2,
    const float* __restrict__ me_b2, const float* __restrict__ ae_w1,
    const float* __restrict__ ae_b1, const float* __restrict__ ae_w2,
    const float* __restrict__ ae_b2, const float* __restrict__ ipw,
    const float* __restrict__ ipb, const float* __restrict__ opw,
    const float* __restrict__ opb, const float* __restrict__ lng,
    const float* __restrict__ lnb, uint* __restrict__ xnh) {
  __shared__ float ss[352];
  __shared__ __align__(16) uint ex[4][176];

  const int tid = threadIdx.x;
  const int wid = tid >> 6, l = tid & 63;
  if (tid < 96) ss[tid] = me_w1[tid];
  if (tid < 32) ss[96 + tid] = me_b1[tid];
  if (tid < 192) ss[128 + tid] = ae_w1[tid];
  if (tid < 32) ss[320 + tid] = ae_b1[tid];

  f16x2 wme2[16], wae2[16], wq[32], wk[32], wv[32], wop[32];
  ldrow<16>(me_w2 + l * 32, wme2);
  ldrow<16>(ae_w2 + l * 32, wae2);
  ldrow<32>(ipw + (size_t)l * 64, wq);
  ldrow<32>(ipw + (size_t)(64 + l) * 64, wk);
  ldrow<32>(ipw + (size_t)(128 + l) * 64, wv);
  ldrow<32>(opw + (size_t)l * 64, wop);
  const float bme2 = me_b2[l], bae2 = ae_b2[l];
  const float bq = ipb[l], bk = ipb[64 + l], bv = ipb[128 + l], bop = opb[l];
  const float gl = lng[l], bl = lnb[l];
  __syncthreads();

  uint* um = ex[wid];
  uint* ua = um + 32;
  uint* e1 = um + 48;
  uint* e2 = um + 80;
  uint* ea = um + 112;
  uint* ec = um + 144;

  for (int base = blockIdx.x * 4; base < NT; base += 4096) {
    const size_t token = base + wid;
    const float4* ob4 = (const float4*)(obs + token * 12);
    float4 o0 = ob4[0], o1 = ob4[1], o2 = ob4[2];

    const int row = l & 31;
    const bool m2h = l >= 32;
    float i0 = m2h ? o0.w : o0.x, i1 = m2h ? o1.x : o0.y, i2 = m2h ? o1.y : o0.z;
    float t1 = ss[96 + row] + i0 * ss[row * 3] + i1 * ss[row * 3 + 1] + i2 * ss[row * 3 + 2];
    t1 = leaky(t1);
    float ta = ss[320 + row] + o1.z * ss[128 + row * 6] + o1.w * ss[128 + row * 6 + 1] +
               o2.x * ss[128 + row * 6 + 2] + o2.y * ss[128 + row * 6 + 3] +
               o2.z * ss[128 + row * 6 + 4] + o2.w * ss[128 + row * 6 + 5];
    ta = leaky(ta);
    float t1p = shflx(t1, 1), tap = shflx(ta, 1);
    if (!(l & 1)) {
      um[l >> 1] = packh2(t1, t1p);
      if (l < 32) ua[l >> 1] = packh2(ta, tap);
    }
    WSYNC();

    float m1e = dot2l<16>(um, wme2, bme2);
    float m2e = dot2l<16>(um + 16, wme2, bme2);
    float ace = dot2l<16>(ua, wae2, bae2);
    float m1p = shflx(m1e, 1), m2p = shflx(m2e, 1), acp = shflx(ace, 1);
    if (!(l & 1)) {
      e1[l >> 1] = packh2(m1e, m1p);
      e2[l >> 1] = packh2(m2e, m2p);
      ea[l >> 1] = packh2(ace, acp);
    }
    WSYNC();

    float q = dot2l<32>(ea, wq, bq);
    float k1 = dot2l<32>(e1, wk, bk);
    float k2 = dot2l<32>(e2, wk, bk);
    float v1 = dot2l<32>(e1, wv, bv);
    float v2 = dot2l<32>(e2, wv, bv);

    float p1 = q * k1, p2 = q * k2;
    p1 += shflx(p1, 1); p2 += shflx(p2, 1);
    p1 += shflx(p1, 2); p2 += shflx(p2, 2);
    p1 += shflx(p1, 4); p2 += shflx(p2, 4);
    p1 += shflx(p1, 8); p2 += shflx(p2, 8);
    float s1 = p1 * 0.25f, s2 = p2 * 0.25f;
    float mx = fmaxf(s1, s2);
    float ev1 = __expf(s1 - mx), ev2 = __expf(s2 - mx);
    float a1 = ev1 / (ev1 + ev2);
    float ctx = a1 * v1 + (1.f - a1) * v2;
    float cxp = shflx(ctx, 1);
    if (!(l & 1)) ec[l >> 1] = packh2(ctx, cxp);
    WSYNC();

    float ao = dot2l<32>(ec, wop, bop);
    float x = ao + ace;
    float s = x, s2s = x * x;
#pragma unroll
    for (int off = 32; off; off >>= 1) {
      s += shflx(s, off);
      s2s += shflx(s2s, off);
    }
    float mu = s * (1.f / 64.f);
    float var = s2s * (1.f / 64.f) - mu * mu;
    float rs = rsqrtf(var + 1e-5f);
    float xn = (x - mu) * rs * gl + bl;
    float xnp = shflx(xn, 1);
    if (!(l & 1)) xnh[token * 32 + (l >> 1)] = packh2(xn, xnp);
  }
}

// ---------------- pre_b (MFMA): xp[NT,384] = xn[NT,64] @ W_ih^T + b ---------
// wave wv owns n-tiles [6wv, 6wv+6); A-frags from xnh (f16 row-major);
// D: col=lane&15, row=quad*4+reg. bf16 epilogue (gru consumes bf16).
__global__ __launch_bounds__(256) void pre_b(const uint* __restrict__ xnh,
                                             const float* __restrict__ wih,
                                             const float* __restrict__ bih,
                                             uint* __restrict__ xp32) {
  const int tid = threadIdx.x;
  const int l = tid & 63, wv = tid >> 6;
  const int n16 = l & 15, q = l >> 4;

  f16x8 Bf[6][2];
  float bias_l[6];
#pragma unroll
  for (int i = 0; i < 6; ++i) {
    const int n = (wv * 6 + i) * 16 + n16;
    const float* wrow = wih + (size_t)n * 64;
    Bf[i][0] = ldw8(wrow + q * 8);
    Bf[i][1] = ldw8(wrow + 32 + q * 8);
    bias_l[i] = bih[n];
  }

  for (int tile = blockIdx.x; tile < NT / 16; tile += gridDim.x) {
    const uint4* arow = (const uint4*)(xnh + (size_t)(tile * 16 + n16) * 32);
    f16x8 A0 = __builtin_bit_cast(f16x8, arow[q]);
    f16x8 A1 = __builtin_bit_cast(f16x8, arow[4 + q]);
#pragma unroll
    for (int i = 0; i < 6; ++i) {
      const int nt = wv * 6 + i;
      f32x4 acc = {0.f, 0.f, 0.f, 0.f};
      acc = __builtin_amdgcn_mfma_f32_16x16x32_f16(A0, Bf[i][0], acc, 0, 0, 0);
      acc = __builtin_amdgcn_mfma_f32_16x16x32_f16(A1, Bf[i][1], acc, 0, 0, 0);
#pragma unroll
      for (int r = 0; r < 4; ++r) {
        uint bv = bf_rne(acc[r] + bias_l[i]);
        uint pv = dpp_xor1_u(bv);
        if (!(l & 1))
          xp32[(size_t)(tile * 16 + q * 4 + r) * 192 + nt * 8 + (n16 >> 1)] =
              bv | (pv << 16);
      }
    }
  }
}

// ---------------- gru: lane-pair split-k + DPP combine (round-10) -----------
__global__ __launch_bounds__(320, 1) void gru_kernel(
    const bf16* __restrict__ xp, const float* __restrict__ hs,
    const float* __restrict__ whh, const float* __restrict__ bhh,
    ushort* __restrict__ gouth, float* __restrict__ hlast) {
  __shared__ __align__(16) uint hbuf[2][64];
  __shared__ __align__(16) uint ring[8 * 192];
  const int tid = threadIdx.x;
  const int b = blockIdx.x;
  const bool comp = tid < 256;
  const int lane = tid & 63;
  const int wv_ = tid >> 6;
  const int m = lane >> 1;
  const int par = lane & 1;
  const int j = (wv_ << 5) + m;
  const int pid = tid - 256;

  f16x2 wr[32], wz[32], wg[32];
  float br = 0.f, bz = 0.f, bg = 0.f, hprev = 0.f;
  const uint* xr32 = (const uint*)(xp + (size_t)b * SS * G3);
  uint a0 = 0, a1 = 0, a2 = 0, c0 = 0, c1 = 0, c2 = 0;
  if (comp) {
    ldrow<32>(whh + (size_t)j * HH + par * 64, wr);
    ldrow<32>(whh + (size_t)(HH + j) * HH + par * 64, wz);
    ldrow<32>(whh + (size_t)(2 * HH + j) * HH + par * 64, wg);
    br = bhh[j]; bz = bhh[HH + j]; bg = bhh[2 * HH + j];
    hprev = hs[b * HH + j];
    if (tid < 64) hbuf[0][tid] = packh2(hs[b * HH + 2 * tid], hs[b * HH + 2 * tid + 1]);
  } else {
    for (int s = 0; s < 4; ++s) {
      const uint* p = xr32 + s * 192 + pid * 3;
      uint v0 = p[0], v1 = p[1], v2 = p[2];
      uint* qq = ring + s * 192 + pid * 3;
      qq[0] = v0; qq[1] = v1; qq[2] = v2;
    }
    const uint* pa = xr32 + 4 * 192 + pid * 3;
    a0 = pa[0]; a1 = pa[1]; a2 = pa[2];
    const uint* pb = xr32 + 5 * 192 + pid * 3;
    c0 = pb[0]; c1 = pb[1]; c2 = pb[2];
  }
  __syncthreads();

  const ushort* ring_us = (const ushort*)ring;
  ushort* grow = gouth + (size_t)b * SS * HH;

#define CSTEP(TT, RD, WRI)                                                     \
  {                                                                            \
    const int slot = (TT) & 7;                                                 \
    uint bxr = ring_us[slot * 384 + j];                                        \
    uint bxz = ring_us[slot * 384 + 128 + j];                                  \
    uint bxg = ring_us[slot * 384 + 256 + j];                                  \
    const uint4* hb4 = (const uint4*)(hbuf[RD] + par * 32);                    \
    float ar = 0.f, az = 0.f, ag = 0.f;                                        \
    _Pragma("unroll") for (int i = 0; i < 8; ++i) {                            \
      uint4 hh = hb4[i];                                                       \
      f16x2 h0 = u2h(hh.x), hA = u2h(hh.y), h2 = u2h(hh.z), h3 = u2h(hh.w);    \
      ar = __builtin_amdgcn_fdot2(h0, wr[4 * i + 0], ar, false);               \
      az = __builtin_amdgcn_fdot2(h0, wz[4 * i + 0], az, false);               \
      ag = __builtin_amdgcn_fdot2(h0, wg[4 * i + 0], ag, false);               \
      ar = __builtin_amdgcn_fdot2(hA, wr[4 * i + 1], ar, false);               \
      az = __builtin_amdgcn_fdot2(hA, wz[4 * i + 1], az, false);               \
      ag = __builtin_amdgcn_fdot2(hA, wg[4 * i + 1], ag, false);               \
      ar = __builtin_amdgcn_fdot2(h2, wr[4 * i + 2], ar, false);               \
      az = __builtin_amdgcn_fdot2(h2, wz[4 * i + 2], az, false);               \
      ag = __builtin_amdgcn_fdot2(h2, wg[4 * i + 2], ag, false);               \
      ar = __builtin_amdgcn_fdot2(h3, wr[4 * i + 3], ar, false);               \
      az = __builtin_amdgcn_fdot2(h3, wz[4 * i + 3], az, false);               \
      ag = __builtin_amdgcn_fdot2(h3, wg[4 * i + 3], ag, false);               \
    }                                                                          \
    ar += dpp_xor1(ar); az += dpp_xor1(az); ag += dpp_xor1(ag);                \
    float xrf = __uint_as_float(bxr << 16);                                    \
    float xzf = __uint_as_float(bxz << 16);                                    \
    float xgf = __uint_as_float(bxg << 16);                                    \
    float r = 1.f / (1.f + __expf(-(xrf + ar + br)));                          \
    float z = 1.f / (1.f + __expf(-(xzf + az + bz)));                          \
    float gp = xgf + r * (ag + bg);                                            \
    float e = __expf(-2.f * fabsf(gp));                                        \
    float th = copysignf((1.f - e) / (1.f + e), gp);                           \
    float hn = (1.f - z) * th + z * hprev;                                     \
    hprev = hn;                                                                \
    if (!par) {                                                                \
      ((ushort*)hbuf[WRI])[j] = (ushort)h1(hn);                                \
      grow[(size_t)(TT)*HH + j] = (ushort)h1(hn);                              \
    }                                                                          \
  }

#define PSTEP(TT, R0, R1, R2)                                                  \
  {                                                                            \
    const int wrow = (TT) + 4;                                                 \
    if (wrow < SS) {                                                           \
      uint* qq = ring + (wrow & 7) * 192 + pid * 3;                            \
      qq[0] = R0; qq[1] = R1; qq[2] = R2;                                      \
      const int lrow = (TT) + 6;                                               \
      if (lrow < SS) {                                                         \
        const uint* p = xr32 + lrow * 192 + pid * 3;                           \
        R0 = p[0]; R1 = p[1]; R2 = p[2];                                       \
      }                                                                        \
    }                                                                          \
  }

  for (int t = 0; t < SS; t += 2) {
    if (comp) {
      CSTEP(t, 0, 1);
    } else {
      PSTEP(t, a0, a1, a2);
    }
    asm volatile("s_waitcnt lgkmcnt(0)\n\ts_barrier" ::: "memory");
    if (comp) {
      CSTEP(t + 1, 1, 0);
    } else {
      PSTEP(t + 1, c0, c1, c2);
    }
    asm volatile("s_waitcnt lgkmcnt(0)\n\ts_barrier" ::: "memory");
  }
#undef CSTEP
#undef PSTEP
  if (comp && !par) hlast[b * HH + j] = hprev;
}

// ---------------- mlp0 (MFMA): f0[NT,128] = leaky(g @ w0^T + b0) ------------
__global__ __launch_bounds__(256) void mlp0(const uint* __restrict__ gh,
                                            const float* __restrict__ w0,
                                            const float* __restrict__ b0,
                                            uint* __restrict__ f0h32) {
  const int tid = threadIdx.x;
  const int l = tid & 63, wv = tid >> 6;
  const int n16 = l & 15, q = l >> 4;

  f16x8 Bf[2][4];
  float bias_l[2];
#pragma unroll
  for (int i = 0; i < 2; ++i) {
    const int n = (wv * 2 + i) * 16 + n16;
    const float* wrow = w0 + (size_t)n * 128;
#pragma unroll
    for (int f = 0; f < 4; ++f) Bf[i][f] = ldw8(wrow + f * 32 + q * 8);
    bias_l[i] = b0[n];
  }

  for (int tile = blockIdx.x; tile < NT / 16; tile += gridDim.x) {
    const uint4* arow = (const uint4*)(gh + (size_t)(tile * 16 + n16) * 64);
    f16x8 A[4];
#pragma unroll
    for (int f = 0; f < 4; ++f) A[f] = __builtin_bit_cast(f16x8, arow[f * 4 + q]);
#pragma unroll
    for (int i = 0; i < 2; ++i) {
      const int nt = wv * 2 + i;
      f32x4 acc = {0.f, 0.f, 0.f, 0.f};
#pragma unroll
      for (int f = 0; f < 4; ++f)
        acc = __builtin_amdgcn_mfma_f32_16x16x32_f16(A[f], Bf[i][f], acc, 0, 0, 0);
#pragma unroll
      for (int r = 0; r < 4; ++r) {
        uint hv = h1(leaky(acc[r] + bias_l[i]));
        uint pv = dpp_xor1_u(hv);
        if (!(l & 1))
          f0h32[(size_t)(tile * 16 + q * 4 + r) * 64 + nt * 8 + (n16 >> 1)] =
              hv | (pv << 16);
      }
    }
  }
}

// ---------------- mlp1 (MFMA): value = leaky(f0@w1^T+b1) @ ow^T + ob --------
__global__ __launch_bounds__(256) void mlp1(const uint* __restrict__ f0h,
                                            const float* __restrict__ w1,
                                            const float* __restrict__ b1,
                                            const float* __restrict__ ow,
                                            const float* __restrict__ obp,
                                            float* __restrict__ value) {
  const int tid = threadIdx.x;
  const int l = tid & 63, wv = tid >> 6;
  const int n16 = l & 15, q = l >> 4;

  f16x8 Bf[8][4];
  float bias_l[8], ow_l[8];
#pragma unroll
  for (int nt = 0; nt < 8; ++nt) {
    const int n = nt * 16 + n16;
    const float* wrow = w1 + (size_t)n * 128;
#pragma unroll
    for (int f = 0; f < 4; ++f) Bf[nt][f] = ldw8(wrow + f * 32 + q * 8);
    bias_l[nt] = b1[n];
    ow_l[nt] = ow[n];
  }
  const float obias = obp[0];

  for (int tile = blockIdx.x * 4 + wv; tile < NT / 16; tile += gridDim.x * 4) {
    const uint4* arow = (const uint4*)(f0h + (size_t)(tile * 16 + n16) * 64);
    f16x8 A[4];
#pragma unroll
    for (int f = 0; f < 4; ++f) A[f] = __builtin_bit_cast(f16x8, arow[f * 4 + q]);
    float s0 = 0.f, s1 = 0.f, s2 = 0.f, s3 = 0.f;
#pragma unroll
    for (int nt = 0; nt < 8; ++nt) {
      f32x4 acc = {0.f, 0.f, 0.f, 0.f};
#pragma unroll
      for (int f = 0; f < 4; ++f)
        acc = __builtin_amdgcn_mfma_f32_16x16x32_f16(A[f], Bf[nt][f], acc, 0, 0, 0);
      s0 += leaky(acc[0] + bias_l[nt]) * ow_l[nt];
      s1 += leaky(acc[1] + bias_l[nt]) * ow_l[nt];
      s2 += leaky(acc[2] + bias_l[nt]) * ow_l[nt];
      s3 += leaky(acc[3] + bias_l[nt]) * ow_l[nt];
    }
#pragma unroll
    for (int mask = 1; mask < 16; mask <<= 1) {
      s0 += shflx(s0, mask);
      s1 += shflx(s1, mask);
      s2 += shflx(s2, mask);
      s3 += shflx(s3, mask);
    }
    if (n16 == 0) {
      value[tile * 16 + q * 4 + 0] = s0 + obias;
      value[tile * 16 + q * 4 + 1] = s1 + obias;
      value[tile * 16 + q * 4 + 2] = s2 + obias;
      value[tile * 16 + q * 4 + 3] = s3 + obias;
    }
  }
}

__global__ void fill_sentinel(float* o, int n) {
  for (int i = blockIdx.x * blockDim.x + threadIdx.x; i < n; i += gridDim.x * blockDim.x)
    o[i] = 999.0f;
}

extern "C" void kernel_launch(void* const* d_in, const int* in_sizes, int n_in,
                              void* d_out, int out_size, void* d_ws, size_t ws_size,
                              hipStream_t stream) {
  const float* obs = (const float*)d_in[0];
  const float* hs = (const float*)d_in[1];
  const float* me_w1 = (const float*)d_in[2];
  const float* me_b1 = (const float*)d_in[3];
  const float* me_w2 = (const float*)d_in[4];
  const float* me_b2 = (const float*)d_in[5];
  const float* ae_w1 = (const float*)d_in[6];
  const float* ae_b1 = (const float*)d_in[7];
  const float* ae_w2 = (const float*)d_in[8];
  const float* ae_b2 = (const float*)d_in[9];
  const float* ipw = (const float*)d_in[10];
  const float* ipb = (const float*)d_in[11];
  const float* opw = (const float*)d_in[12];
  const float* opb = (const float*)d_in[13];
  const float* lng = (const float*)d_in[14];
  const float* lnb = (const float*)d_in[15];
  const float* wih = (const float*)d_in[16];
  const float* whh = (const float*)d_in[17];
  const float* bih = (const float*)d_in[18];
  const float* bhh = (const float*)d_in[19];
  const float* w0 = (const float*)d_in[20];
  const float* b0 = (const float*)d_in[21];
  const float* w1 = (const float*)d_in[22];
  const float* b1 = (const float*)d_in[23];
  const float* ow = (const float*)d_in[24];
  const float* ob = (const float*)d_in[25];

  // workspace (128 MiB):
  //  region A [0, 100.66MB): xp bf16 [NT,384]; later f0h f16 [NT,128]
  //  region B [100.66MB, 134.22MB): xnh f16-pairs [NT,32]; later gouth f16 [NT,128]
  const size_t regA_bytes = (size_t)NT * G3 * sizeof(bf16);
  const size_t regB_bytes = (size_t)NT * 64 * sizeof(uint);
  const size_t need = regA_bytes + regB_bytes;  // 134,217,728
  float* out = (float*)d_out;
  if (ws_size < need) {
    fill_sentinel<<<288, 256, 0, stream>>>(out, out_size);
    return;
  }

  char* ws = (char*)d_ws;
  bf16* xp = (bf16*)ws;
  uint* f0h = (uint*)ws;
  uint* xnh = (uint*)(ws + regA_bytes);
  ushort* gouth = (ushort*)(ws + regA_bytes);

  pre_a<<<1024, 256, 0, stream>>>(obs, me_w1, me_b1, me_w2, me_b2, ae_w1, ae_b1,
                                  ae_w2, ae_b2, ipw, ipb, opw, opb, lng, lnb, xnh);
  pre_b<<<1024, 256, 0, stream>>>(xnh, wih, bih, (uint*)xp);
  gru_kernel<<<BB, 320, 0, stream>>>(xp, hs, whh, bhh, gouth, out + NT);
  mlp0<<<1024, 256, 0, stream>>>((const uint*)gouth, w0, b0, f0h);
  mlp1<<<1024, 256, 0, stream>>>(f0h, w1, b1, ow, ob, out);
}

// Round 12
// 833.852 us; speedup vs baseline: 2.3981x; 1.1544x over previous
//
#include <hip/hip_runtime.h>
#include <hip/hip_bf16.h>

#define BB 128
#define SS 1024
#define HH 128
#define G3 384
#define NT (BB * SS)   // 131072 tokens

typedef __hip_bfloat16 bf16;
typedef unsigned int uint;
typedef unsigned short ushort;
typedef _Float16 f16;
typedef f16 f16x2 __attribute__((ext_vector_type(2)));
typedef f16 f16x8 __attribute__((ext_vector_type(8)));
typedef float f32x4 __attribute__((ext_vector_type(4)));

__device__ __forceinline__ float leaky(float x) { return x >= 0.f ? x : 0.01f * x; }
__device__ __forceinline__ f16x2 u2h(uint u) { return __builtin_bit_cast(f16x2, u); }
__device__ __forceinline__ uint packh2(float a, float b) {
  f16x2 h; h.x = (f16)a; h.y = (f16)b;
  return __builtin_bit_cast(uint, h);
}
__device__ __forceinline__ uint h1(float a) {
  return (uint)__builtin_bit_cast(ushort, (f16)a);
}
__device__ __forceinline__ uint bf_rne(float f) {
  uint u = __float_as_uint(f);
  return (u + 0x7FFFu + ((u >> 16) & 1u)) >> 16;
}
__device__ __forceinline__ float shflx(float v, int m) { return __shfl_xor(v, m, 64); }
__device__ __forceinline__ float dpp_xor1(float v) {
  int i = __builtin_bit_cast(int, v);
  i = __builtin_amdgcn_update_dpp(0, i, 0xB1, 0xF, 0xF, true);
  return __builtin_bit_cast(float, i);
}
__device__ __forceinline__ uint dpp_xor1_u(uint v) {
  int i = __builtin_amdgcn_update_dpp(0, (int)v, 0xB1, 0xF, 0xF, true);
  return (uint)i;
}
#define WSYNC() asm volatile("s_waitcnt lgkmcnt(0)" ::: "memory")

template <int NP>
__device__ __forceinline__ void ldrow(const float* __restrict__ p, f16x2* w) {
#pragma unroll
  for (int i = 0; i < NP; ++i) {
    f16x2 h; h.x = (f16)p[2 * i]; h.y = (f16)p[2 * i + 1];
    w[i] = h;
  }
}
__device__ __forceinline__ f16x8 ldw8(const float* __restrict__ p) {
  f16x8 v;
#pragma unroll
  for (int j = 0; j < 8; ++j) v[j] = (f16)p[j];
  return v;
}
template <int NP>
__device__ __forceinline__ float dot2l(const uint* __restrict__ x,
                                       const f16x2* __restrict__ w, float acc) {
#pragma unroll
  for (int i = 0; i < NP / 4; ++i) {
    uint4 uu = ((const uint4*)x)[i];
    acc = __builtin_amdgcn_fdot2(u2h(uu.x), w[4 * i + 0], acc, false);
    acc = __builtin_amdgcn_fdot2(u2h(uu.y), w[4 * i + 1], acc, false);
    acc = __builtin_amdgcn_fdot2(u2h(uu.z), w[4 * i + 2], acc, false);
    acc = __builtin_amdgcn_fdot2(u2h(uu.w), w[4 * i + 3], acc, false);
  }
  return acc;
}
// 4 packed pairs (x) vs 4 packed pairs (w)
__device__ __forceinline__ float d4(uint4 x, uint4 w, float acc) {
  acc = __builtin_amdgcn_fdot2(u2h(x.x), u2h(w.x), acc, false);
  acc = __builtin_amdgcn_fdot2(u2h(x.y), u2h(w.y), acc, false);
  acc = __builtin_amdgcn_fdot2(u2h(x.z), u2h(w.z), acc, false);
  acc = __builtin_amdgcn_fdot2(u2h(x.w), u2h(w.w), acc, false);
  return acc;
}

// ---------------- pre_a: encoders + attention + LN -> xnh (f16 pairs) -------
// Stage-3/out-proj weights in chunk-major LDS (w4[c][row], lane-consecutive
// 16B = conflict-free b128); enc2 weights stay in registers (32 VGPR).
// __launch_bounds__(256,4): cap 128 VGPR -> 4 waves/SIMD.
__global__ __launch_bounds__(256, 4) void pre_a(
    const float* __restrict__ obs, const float* __restrict__ me_w1,
    const float* __restrict__ me_b1, const float* __restrict__ me_w2,
    const float* __restrict__ me_b2, const float* __restrict__ ae_w1,
    const float* __restrict__ ae_b1, const float* __restrict__ ae_w2,
    const float* __restrict__ ae_b2, const float* __restrict__ ipw,
    const float* __restrict__ ipb, const float* __restrict__ opw,
    const float* __restrict__ opb, const float* __restrict__ lng,
    const float* __restrict__ lnb, uint* __restrict__ xnh) {
  __shared__ float ss[352];
  __shared__ __align__(16) uint4 w4[8 * 256];  // 32 KB: [chunk c][row r]
  __shared__ __align__(16) uint ex[4][176];

  const int tid = threadIdx.x;
  const int wid = tid >> 6, l = tid & 63;
  if (tid < 96) ss[tid] = me_w1[tid];
  if (tid < 32) ss[96 + tid] = me_b1[tid];
  if (tid < 192) ss[128 + tid] = ae_w1[tid];
  if (tid < 32) ss[320 + tid] = ae_b1[tid];

  // stage-3 weights: rows 0..63 q, 64..127 k, 128..191 v, 192..255 out_proj
  for (int idx = tid; idx < 2048; idx += 256) {
    const int r = idx & 255, c = idx >> 8;
    const float* src =
        (r < 192 ? ipw + (size_t)r * 64 : opw + (size_t)(r - 192) * 64) + c * 8;
    uint4 u;
    u.x = packh2(src[0], src[1]);
    u.y = packh2(src[2], src[3]);
    u.z = packh2(src[4], src[5]);
    u.w = packh2(src[6], src[7]);
    w4[(c << 8) + r] = u;
  }

  f16x2 wme2[16], wae2[16];
  ldrow<16>(me_w2 + l * 32, wme2);
  ldrow<16>(ae_w2 + l * 32, wae2);
  const float bme2 = me_b2[l], bae2 = ae_b2[l];
  const float bq = ipb[l], bk = ipb[64 + l], bv = ipb[128 + l], bop = opb[l];
  const float gl = lng[l], bl = lnb[l];
  __syncthreads();

  uint* um = ex[wid];
  uint* ua = um + 32;
  uint* e1 = um + 48;
  uint* e2 = um + 80;
  uint* ea = um + 112;
  uint* ec = um + 144;

  for (int base = blockIdx.x * 4; base < NT; base += 4096) {
    const size_t token = base + wid;
    const float4* ob4 = (const float4*)(obs + token * 12);
    float4 o0 = ob4[0], o1 = ob4[1], o2 = ob4[2];

    // stage 1: encoder hidden layers
    const int row = l & 31;
    const bool m2h = l >= 32;
    float i0 = m2h ? o0.w : o0.x, i1 = m2h ? o1.x : o0.y, i2 = m2h ? o1.y : o0.z;
    float t1 = ss[96 + row] + i0 * ss[row * 3] + i1 * ss[row * 3 + 1] + i2 * ss[row * 3 + 2];
    t1 = leaky(t1);
    float ta = ss[320 + row] + o1.z * ss[128 + row * 6] + o1.w * ss[128 + row * 6 + 1] +
               o2.x * ss[128 + row * 6 + 2] + o2.y * ss[128 + row * 6 + 3] +
               o2.z * ss[128 + row * 6 + 4] + o2.w * ss[128 + row * 6 + 5];
    ta = leaky(ta);
    float t1p = shflx(t1, 1), tap = shflx(ta, 1);
    if (!(l & 1)) {
      um[l >> 1] = packh2(t1, t1p);
      if (l < 32) ua[l >> 1] = packh2(ta, tap);
    }
    WSYNC();

    // stage 2: encoder output layers (register weights)
    float m1e = dot2l<16>(um, wme2, bme2);
    float m2e = dot2l<16>(um + 16, wme2, bme2);
    float ace = dot2l<16>(ua, wae2, bae2);
    float m1p = shflx(m1e, 1), m2p = shflx(m2e, 1), acp = shflx(ace, 1);
    if (!(l & 1)) {
      e1[l >> 1] = packh2(m1e, m1p);
      e2[l >> 1] = packh2(m2e, m2p);
      ea[l >> 1] = packh2(ace, acp);
    }
    WSYNC();

    // stage 3: q,k1,k2,v1,v2 from chunk-major LDS weights (k/v rows shared)
    float q = bq, k1 = bk, k2 = bk, v1 = bv, v2 = bv;
    {
      const uint4* xe1 = (const uint4*)e1;
      const uint4* xe2 = (const uint4*)e2;
      const uint4* xea = (const uint4*)ea;
#pragma unroll
      for (int c = 0; c < 8; ++c) {
        uint4 x1 = xe1[c], x2 = xe2[c], xa = xea[c];
        uint4 uq = w4[(c << 8) + l];
        uint4 uk = w4[(c << 8) + 64 + l];
        uint4 uv = w4[(c << 8) + 128 + l];
        q = d4(xa, uq, q);
        k1 = d4(x1, uk, k1);
        k2 = d4(x2, uk, k2);
        v1 = d4(x1, uv, v1);
        v2 = d4(x2, uv, v2);
      }
    }

    // stage 4: attention via shfl-reduce within 16-lane heads
    float p1 = q * k1, p2 = q * k2;
    p1 += shflx(p1, 1); p2 += shflx(p2, 1);
    p1 += shflx(p1, 2); p2 += shflx(p2, 2);
    p1 += shflx(p1, 4); p2 += shflx(p2, 4);
    p1 += shflx(p1, 8); p2 += shflx(p2, 8);
    float s1 = p1 * 0.25f, s2 = p2 * 0.25f;
    float mx = fmaxf(s1, s2);
    float ev1 = __expf(s1 - mx), ev2 = __expf(s2 - mx);
    float a1 = ev1 / (ev1 + ev2);
    float ctx = a1 * v1 + (1.f - a1) * v2;
    float cxp = shflx(ctx, 1);
    if (!(l & 1)) ec[l >> 1] = packh2(ctx, cxp);
    WSYNC();

    // out_proj (LDS rows 192..255) + residual + LayerNorm
    float ao = bop;
    {
      const uint4* xec = (const uint4*)ec;
#pragma unroll
      for (int c = 0; c < 8; ++c) {
        ao = d4(xec[c], w4[(c << 8) + 192 + l], ao);
      }
    }
    float x = ao + ace;
    float s = x, s2s = x * x;
#pragma unroll
    for (int off = 32; off; off >>= 1) {
      s += shflx(s, off);
      s2s += shflx(s2s, off);
    }
    float mu = s * (1.f / 64.f);
    float var = s2s * (1.f / 64.f) - mu * mu;
    float rs = rsqrtf(var + 1e-5f);
    float xn = (x - mu) * rs * gl + bl;
    float xnp = shflx(xn, 1);
    if (!(l & 1)) xnh[token * 32 + (l >> 1)] = packh2(xn, xnp);
  }
}

// ---------------- pre_b (MFMA): xp[NT,384] = xn[NT,64] @ W_ih^T + b ---------
__global__ __launch_bounds__(256) void pre_b(const uint* __restrict__ xnh,
                                             const float* __restrict__ wih,
                                             const float* __restrict__ bih,
                                             uint* __restrict__ xp32) {
  const int tid = threadIdx.x;
  const int l = tid & 63, wv = tid >> 6;
  const int n16 = l & 15, q = l >> 4;

  f16x8 Bf[6][2];
  float bias_l[6];
#pragma unroll
  for (int i = 0; i < 6; ++i) {
    const int n = (wv * 6 + i) * 16 + n16;
    const float* wrow = wih + (size_t)n * 64;
    Bf[i][0] = ldw8(wrow + q * 8);
    Bf[i][1] = ldw8(wrow + 32 + q * 8);
    bias_l[i] = bih[n];
  }

  for (int tile = blockIdx.x; tile < NT / 16; tile += gridDim.x) {
    const uint4* arow = (const uint4*)(xnh + (size_t)(tile * 16 + n16) * 32);
    f16x8 A0 = __builtin_bit_cast(f16x8, arow[q]);
    f16x8 A1 = __builtin_bit_cast(f16x8, arow[4 + q]);
#pragma unroll
    for (int i = 0; i < 6; ++i) {
      const int nt = wv * 6 + i;
      f32x4 acc = {0.f, 0.f, 0.f, 0.f};
      acc = __builtin_amdgcn_mfma_f32_16x16x32_f16(A0, Bf[i][0], acc, 0, 0, 0);
      acc = __builtin_amdgcn_mfma_f32_16x16x32_f16(A1, Bf[i][1], acc, 0, 0, 0);
#pragma unroll
      for (int r = 0; r < 4; ++r) {
        uint bv = bf_rne(acc[r] + bias_l[i]);
        uint pv = dpp_xor1_u(bv);
        if (!(l & 1))
          xp32[(size_t)(tile * 16 + q * 4 + r) * 192 + nt * 8 + (n16 >> 1)] =
              bv | (pv << 16);
      }
    }
  }
}

// ---------------- gru: lane-pair split-k + DPP combine (round-10, control) --
__global__ __launch_bounds__(320, 1) void gru_kernel(
    const bf16* __restrict__ xp, const float* __restrict__ hs,
    const float* __restrict__ whh, const float* __restrict__ bhh,
    ushort* __restrict__ gouth, float* __restrict__ hlast) {
  __shared__ __align__(16) uint hbuf[2][64];
  __shared__ __align__(16) uint ring[8 * 192];
  const int tid = threadIdx.x;
  const int b = blockIdx.x;
  const bool comp = tid < 256;
  const int lane = tid & 63;
  const int wv_ = tid >> 6;
  const int m = lane >> 1;
  const int par = lane & 1;
  const int j = (wv_ << 5) + m;
  const int pid = tid - 256;

  f16x2 wr[32], wz[32], wg[32];
  float br = 0.f, bz = 0.f, bg = 0.f, hprev = 0.f;
  const uint* xr32 = (const uint*)(xp + (size_t)b * SS * G3);
  uint a0 = 0, a1 = 0, a2 = 0, c0 = 0, c1 = 0, c2 = 0;
  if (comp) {
    ldrow<32>(whh + (size_t)j * HH + par * 64, wr);
    ldrow<32>(whh + (size_t)(HH + j) * HH + par * 64, wz);
    ldrow<32>(whh + (size_t)(2 * HH + j) * HH + par * 64, wg);
    br = bhh[j]; bz = bhh[HH + j]; bg = bhh[2 * HH + j];
    hprev = hs[b * HH + j];
    if (tid < 64) hbuf[0][tid] = packh2(hs[b * HH + 2 * tid], hs[b * HH + 2 * tid + 1]);
  } else {
    for (int s = 0; s < 4; ++s) {
      const uint* p = xr32 + s * 192 + pid * 3;
      uint v0 = p[0], v1 = p[1], v2 = p[2];
      uint* qq = ring + s * 192 + pid * 3;
      qq[0] = v0; qq[1] = v1; qq[2] = v2;
    }
    const uint* pa = xr32 + 4 * 192 + pid * 3;
    a0 = pa[0]; a1 = pa[1]; a2 = pa[2];
    const uint* pb = xr32 + 5 * 192 + pid * 3;
    c0 = pb[0]; c1 = pb[1]; c2 = pb[2];
  }
  __syncthreads();

  const ushort* ring_us = (const ushort*)ring;
  ushort* grow = gouth + (size_t)b * SS * HH;

#define CSTEP(TT, RD, WRI)                                                     \
  {                                                                            \
    const int slot = (TT) & 7;                                                 \
    uint bxr = ring_us[slot * 384 + j];                                        \
    uint bxz = ring_us[slot * 384 + 128 + j];                                  \
    uint bxg = ring_us[slot * 384 + 256 + j];                                  \
    const uint4* hb4 = (const uint4*)(hbuf[RD] + par * 32);                    \
    float ar = 0.f, az = 0.f, ag = 0.f;                                        \
    _Pragma("unroll") for (int i = 0; i < 8; ++i) {                            \
      uint4 hh = hb4[i];                                                       \
      f16x2 h0 = u2h(hh.x), hA = u2h(hh.y), h2 = u2h(hh.z), h3 = u2h(hh.w);    \
      ar = __builtin_amdgcn_fdot2(h0, wr[4 * i + 0], ar, false);               \
      az = __builtin_amdgcn_fdot2(h0, wz[4 * i + 0], az, false);               \
      ag = __builtin_amdgcn_fdot2(h0, wg[4 * i + 0], ag, false);               \
      ar = __builtin_amdgcn_fdot2(hA, wr[4 * i + 1], ar, false);               \
      az = __builtin_amdgcn_fdot2(hA, wz[4 * i + 1], az, false);               \
      ag = __builtin_amdgcn_fdot2(hA, wg[4 * i + 1], ag, false);               \
      ar = __builtin_amdgcn_fdot2(h2, wr[4 * i + 2], ar, false);               \
      az = __builtin_amdgcn_fdot2(h2, wz[4 * i + 2], az, false);               \
      ag = __builtin_amdgcn_fdot2(h2, wg[4 * i + 2], ag, false);               \
      ar = __builtin_amdgcn_fdot2(h3, wr[4 * i + 3], ar, false);               \
      az = __builtin_amdgcn_fdot2(h3, wz[4 * i + 3], az, false);               \
      ag = __builtin_amdgcn_fdot2(h3, wg[4 * i + 3], ag, false);               \
    }                                                                          \
    ar += dpp_xor1(ar); az += dpp_xor1(az); ag += dpp_xor1(ag);                \
    float xrf = __uint_as_float(bxr << 16);                                    \
    float xzf = __uint_as_float(bxz << 16);                                    \
    float xgf = __uint_as_float(bxg << 16);                                    \
    float r = 1.f / (1.f + __expf(-(xrf + ar + br)));                          \
    float z = 1.f / (1.f + __expf(-(xzf + az + bz)));                          \
    float gp = xgf + r * (ag + bg);                                            \
    float e = __expf(-2.f * fabsf(gp));                                        \
    float th = copysignf((1.f - e) / (1.f + e), gp);                           \
    float hn = (1.f - z) * th + z * hprev;                                     \
    hprev = hn;                                                                \
    if (!par) {                                                                \
      ((ushort*)hbuf[WRI])[j] = (ushort)h1(hn);                                \
      grow[(size_t)(TT)*HH + j] = (ushort)h1(hn);                              \
    }                                                                          \
  }

#define PSTEP(TT, R0, R1, R2)                                                  \
  {                                                                            \
    const int wrow = (TT) + 4;                                                 \
    if (wrow < SS) {                                                           \
      uint* qq = ring + (wrow & 7) * 192 + pid * 3;                            \
      qq[0] = R0; qq[1] = R1; qq[2] = R2;                                      \
      const int lrow = (TT) + 6;                                               \
      if (lrow < SS) {                                                         \
        const uint* p = xr32 + lrow * 192 + pid * 3;                           \
        R0 = p[0]; R1 = p[1]; R2 = p[2];                                       \
      }                                                                        \
    }                                                                          \
  }

  for (int t = 0; t < SS; t += 2) {
    if (comp) {
      CSTEP(t, 0, 1);
    } else {
      PSTEP(t, a0, a1, a2);
    }
    asm volatile("s_waitcnt lgkmcnt(0)\n\ts_barrier" ::: "memory");
    if (comp) {
      CSTEP(t + 1, 1, 0);
    } else {
      PSTEP(t + 1, c0, c1, c2);
    }
    asm volatile("s_waitcnt lgkmcnt(0)\n\ts_barrier" ::: "memory");
  }
#undef CSTEP
#undef PSTEP
  if (comp && !par) hlast[b * HH + j] = hprev;
}

// ---------------- mlp0 (MFMA): f0[NT,128] = leaky(g @ w0^T + b0) ------------
__global__ __launch_bounds__(256) void mlp0(const uint* __restrict__ gh,
                                            const float* __restrict__ w0,
                                            const float* __restrict__ b0,
                                            uint* __restrict__ f0h32) {
  const int tid = threadIdx.x;
  const int l = tid & 63, wv = tid >> 6;
  const int n16 = l & 15, q = l >> 4;

  f16x8 Bf[2][4];
  float bias_l[2];
#pragma unroll
  for (int i = 0; i < 2; ++i) {
    const int n = (wv * 2 + i) * 16 + n16;
    const float* wrow = w0 + (size_t)n * 128;
#pragma unroll
    for (int f = 0; f < 4; ++f) Bf[i][f] = ldw8(wrow + f * 32 + q * 8);
    bias_l[i] = b0[n];
  }

  for (int tile = blockIdx.x; tile < NT / 16; tile += gridDim.x) {
    const uint4* arow = (const uint4*)(gh + (size_t)(tile * 16 + n16) * 64);
    f16x8 A[4];
#pragma unroll
    for (int f = 0; f < 4; ++f) A[f] = __builtin_bit_cast(f16x8, arow[f * 4 + q]);
#pragma unroll
    for (int i = 0; i < 2; ++i) {
      const int nt = wv * 2 + i;
      f32x4 acc = {0.f, 0.f, 0.f, 0.f};
#pragma unroll
      for (int f = 0; f < 4; ++f)
        acc = __builtin_amdgcn_mfma_f32_16x16x32_f16(A[f], Bf[i][f], acc, 0, 0, 0);
#pragma unroll
      for (int r = 0; r < 4; ++r) {
        uint hv = h1(leaky(acc[r] + bias_l[i]));
        uint pv = dpp_xor1_u(hv);
        if (!(l & 1))
          f0h32[(size_t)(tile * 16 + q * 4 + r) * 64 + nt * 8 + (n16 >> 1)] =
              hv | (pv << 16);
      }
    }
  }
}

// ---------------- mlp1 (MFMA): value = leaky(f0@w1^T+b1) @ ow^T + ob --------
__global__ __launch_bounds__(256) void mlp1(const uint* __restrict__ f0h,
                                            const float* __restrict__ w1,
                                            const float* __restrict__ b1,
                                            const float* __restrict__ ow,
                                            const float* __restrict__ obp,
                                            float* __restrict__ value) {
  const int tid = threadIdx.x;
  const int l = tid & 63, wv = tid >> 6;
  const int n16 = l & 15, q = l >> 4;

  f16x8 Bf[8][4];
  float bias_l[8], ow_l[8];
#pragma unroll
  for (int nt = 0; nt < 8; ++nt) {
    const int n = nt * 16 + n16;
    const float* wrow = w1 + (size_t)n * 128;
#pragma unroll
    for (int f = 0; f < 4; ++f) Bf[nt][f] = ldw8(wrow + f * 32 + q * 8);
    bias_l[nt] = b1[n];
    ow_l[nt] = ow[n];
  }
  const float obias = obp[0];

  for (int tile = blockIdx.x * 4 + wv; tile < NT / 16; tile += gridDim.x * 4) {
    const uint4* arow = (const uint4*)(f0h + (size_t)(tile * 16 + n16) * 64);
    f16x8 A[4];
#pragma unroll
    for (int f = 0; f < 4; ++f) A[f] = __builtin_bit_cast(f16x8, arow[f * 4 + q]);
    float s0 = 0.f, s1 = 0.f, s2 = 0.f, s3 = 0.f;
#pragma unroll
    for (int nt = 0; nt < 8; ++nt) {
      f32x4 acc = {0.f, 0.f, 0.f, 0.f};
#pragma unroll
      for (int f = 0; f < 4; ++f)
        acc = __builtin_amdgcn_mfma_f32_16x16x32_f16(A[f], Bf[nt][f], acc, 0, 0, 0);
      s0 += leaky(acc[0] + bias_l[nt]) * ow_l[nt];
      s1 += leaky(acc[1] + bias_l[nt]) * ow_l[nt];
      s2 += leaky(acc[2] + bias_l[nt]) * ow_l[nt];
      s3 += leaky(acc[3] + bias_l[nt]) * ow_l[nt];
    }
#pragma unroll
    for (int mask = 1; mask < 16; mask <<= 1) {
      s0 += shflx(s0, mask);
      s1 += shflx(s1, mask);
      s2 += shflx(s2, mask);
      s3 += shflx(s3, mask);
    }
    if (n16 == 0) {
      value[tile * 16 + q * 4 + 0] = s0 + obias;
      value[tile * 16 + q * 4 + 1] = s1 + obias;
      value[tile * 16 + q * 4 + 2] = s2 + obias;
      value[tile * 16 + q * 4 + 3] = s3 + obias;
    }
  }
}

__global__ void fill_sentinel(float* o, int n) {
  for (int i = blockIdx.x * blockDim.x + threadIdx.x; i < n; i += gridDim.x * blockDim.x)
    o[i] = 999.0f;
}

extern "C" void kernel_launch(void* const* d_in, const int* in_sizes, int n_in,
                              void* d_out, int out_size, void* d_ws, size_t ws_size,
                              hipStream_t stream) {
  const float* obs = (const float*)d_in[0];
  const float* hs = (const float*)d_in[1];
  const float* me_w1 = (const float*)d_in[2];
  const float* me_b1 = (const float*)d_in[3];
  const float* me_w2 = (const float*)d_in[4];
  const float* me_b2 = (const float*)d_in[5];
  const float* ae_w1 = (const float*)d_in[6];
  const float* ae_b1 = (const float*)d_in[7];
  const float* ae_w2 = (const float*)d_in[8];
  const float* ae_b2 = (const float*)d_in[9];
  const float* ipw = (const float*)d_in[10];
  const float* ipb = (const float*)d_in[11];
  const float* opw = (const float*)d_in[12];
  const float* opb = (const float*)d_in[13];
  const float* lng = (const float*)d_in[14];
  const float* lnb = (const float*)d_in[15];
  const float* wih = (const float*)d_in[16];
  const float* whh = (const float*)d_in[17];
  const float* bih = (const float*)d_in[18];
  const float* bhh = (const float*)d_in[19];
  const float* w0 = (const float*)d_in[20];
  const float* b0 = (const float*)d_in[21];
  const float* w1 = (const float*)d_in[22];
  const float* b1 = (const float*)d_in[23];
  const float* ow = (const float*)d_in[24];
  const float* ob = (const float*)d_in[25];

  // workspace (128 MiB):
  //  region A [0, 100.66MB): xp bf16 [NT,384]; later f0h f16 [NT,128]
  //  region B [100.66MB, 134.22MB): xnh f16-pairs [NT,32]; later gouth f16 [NT,128]
  const size_t regA_bytes = (size_t)NT * G3 * sizeof(bf16);
  const size_t regB_bytes = (size_t)NT * 64 * sizeof(uint);
  const size_t need = regA_bytes + regB_bytes;  // 134,217,728
  float* out = (float*)d_out;
  if (ws_size < need) {
    fill_sentinel<<<288, 256, 0, stream>>>(out, out_size);
    return;
  }

  char* ws = (char*)d_ws;
  bf16* xp = (bf16*)ws;
  uint* f0h = (uint*)ws;
  uint* xnh = (uint*)(ws + regA_bytes);
  ushort* gouth = (ushort*)(ws + regA_bytes);

  pre_a<<<1024, 256, 0, stream>>>(obs, me_w1, me_b1, me_w2, me_b2, ae_w1, ae_b1,
                                  ae_w2, ae_b2, ipw, ipb, opw, opb, lng, lnb, xnh);
  pre_b<<<1024, 256, 0, stream>>>(xnh, wih, bih, (uint*)xp);
  gru_kernel<<<BB, 320, 0, stream>>>(xp, hs, whh, bhh, gouth, out + NT);
  mlp0<<<1024, 256, 0, stream>>>((const uint*)gouth, w0, b0, f0h);
  mlp1<<<1024, 256, 0, stream>>>(f0h, w1, b1, ow, ob, out);
}